// Round 14
// baseline (630.172 us; speedup 1.0000x reference)
//
#include <hip/hip_runtime.h>
#include <math.h>

// ---------------------------------------------------------------------------
// DAttention forward. R14: emb conv re-tiled for 4 blocks/CU (16-wide o-tile,
// single-buffer LDS + reg prefetch, grid 1024); dw9+cotail fused. 16 dispatches.
// Dims: B=4, C=512, H=W=32, G=2, gc=256, BG=8, heads=8, hc=64, mh=8, mhd=32.
// ---------------------------------------------------------------------------

static constexpr int HW = 1024;

typedef __attribute__((ext_vector_type(8))) short bf16x8;
typedef __attribute__((ext_vector_type(4))) float f32x4;

union V16u { int4 i4; ushort u[8]; };

__device__ __forceinline__ float gelu_exact(float v) {
  return 0.5f * v * (1.0f + erff(v * 0.7071067811865475f));
}

__device__ __forceinline__ ushort bf16_rne(float v) {
  unsigned int b = __float_as_uint(v);
  return (ushort)((b + 0x7fffu + ((b >> 16) & 1u)) >> 16);
}

__device__ __forceinline__ void split2(float v, ushort& h, ushort& l) {
  h = bf16_rne(v);
  l = bf16_rne(v - __uint_as_float(((unsigned int)h) << 16));
}

// ---------------- weight frag body (shared); scale folded into weights
__device__ __forceinline__ void wfrag_body(const float* __restrict__ W, int K, int KC,
                                           ushort* __restrict__ dh, ushort* __restrict__ dl,
                                           int gtid, float scale) {
  int l = gtid & 63; int fr = gtid >> 6;
  int kc = fr % KC; int ot = fr / KC;
  int lr = l & 15, lu = l >> 4;
  const float* sp = W + (size_t)(ot * 16 + lr) * K + kc * 32 + lu * 8;
  V16u hi, lo;
#pragma unroll
  for (int j = 0; j < 8; ++j) split2(sp[j] * scale, hi.u[j], lo.u[j]);
  *(int4*)(dh + (size_t)gtid * 8) = hi.i4;
  *(int4*)(dl + (size_t)gtid * 8) = lo.i4;
}

// ---------------- MEGA-PREP (unchanged from R13). grid 6370.
__global__ void k_prep_all(
    const float* __restrict__ emb_w, const float* __restrict__ tgt,
    const float* __restrict__ refp,
    const float* q_w, const float* k_w, const float* v_w, const float* o_w,
    const float* mq_w, const float* mkv_w, const float* mp_w,
    const float* f1_w, const float* f2_w, const float* dw9_w,
    const float* q_b, const float* mq_b, const float* mkv_b,
    const float* k_b, const float* v_b,
    ushort* __restrict__ WtEH, ushort* __restrict__ WtEL,
    ushort* __restrict__ XtH, ushort* __restrict__ XtL,
    ushort* qh, ushort* ql, ushort* kvh, ushort* kvl,
    ushort* oh, ushort* ol, ushort* mqkvh, ushort* mqkvl,
    ushort* mph, ushort* mpl, ushort* f1h, ushort* f1l, ushort* f2h, ushort* f2l,
    float* wt9, float* biasmb, float* biaskv, float* biasq,
    ushort* tgtfh, ushort* tgtfl) {
  int bid = blockIdx.x, tid = threadIdx.x;
  if (bid < 2048) {                      // emb weights -> [9][512][1024] hi/lo
    int idx = bid * 256 + tid;
    int o = idx >> 10, ci = idx & 1023;
    const float* src = emb_w + (size_t)idx * 9;
#pragma unroll
    for (int t = 0; t < 9; ++t) {
      ushort h, l; split2(src[t], h, l);
      size_t oo = ((size_t)(t * 512 + o)) * 1024 + ci;
      WtEH[oo] = h; WtEL[oo] = l;
    }
  } else if (bid < 4360) {               // inputs -> [4][34][34][1024] hi/lo
    int idx = (bid - 2048) * 256 + tid;
    int xp = idx % 34; int r = idx / 34;
    int g8 = r & 127; r >>= 7;
    int yp = r % 34; int b = r / 34;
    int y = yp - 1, x = xp - 1;
    bool valid = (unsigned)y < 32u && (unsigned)x < 32u;
    V16u hi, lo;
    const float* in = (g8 < 64) ? (tgt + ((size_t)(b * 512 + g8 * 8)) * HW)
                                : (refp + ((size_t)(b * 512 + (g8 - 64) * 8)) * HW);
#pragma unroll
    for (int j = 0; j < 8; ++j) {
      float v = valid ? in[(size_t)j * HW + y * 32 + x] : 0.f;
      split2(v, hi.u[j], lo.u[j]);
    }
    size_t oo = (((size_t)(b * 34 + yp)) * 34 + xp) * 1024 + g8 * 8;
    *(int4*)(XtH + oo) = hi.i4;
    *(int4*)(XtL + oo) = lo.i4;
  }
  else if (bid < 4488) wfrag_body(q_w, 512, 16, qh, ql, (bid - 4360) * 256 + tid, 0.125f);
  else if (bid < 4616) wfrag_body(k_w, 512, 16, kvh, kvl, (bid - 4488) * 256 + tid, 1.f);
  else if (bid < 4744) wfrag_body(v_w, 512, 16, kvh + 262144, kvl + 262144,
                                  (bid - 4616) * 256 + tid, 1.f);
  else if (bid < 4872) wfrag_body(o_w, 512, 16, oh, ol, (bid - 4744) * 256 + tid, 1.f);
  else if (bid < 4904) wfrag_body(mq_w, 256, 8, mqkvh, mqkvl, (bid - 4872) * 256 + tid,
                                  0.17677669529663689f);
  else if (bid < 4968) wfrag_body(mkv_w, 256, 8, mqkvh + 65536, mqkvl + 65536,
                                  (bid - 4904) * 256 + tid, 1.f);
  else if (bid < 5000) wfrag_body(mp_w, 256, 8, mph, mpl, (bid - 4968) * 256 + tid, 1.f);
  else if (bid < 5128) wfrag_body(f1_w, 256, 8, f1h, f1l, (bid - 5000) * 256 + tid, 1.f);
  else if (bid < 5256) wfrag_body(f2_w, 1024, 32, f2h, f2l, (bid - 5128) * 256 + tid, 1.f);
  else if (bid < 5337) {                 // dw9 weight transpose [81][256]
    int idx = (bid - 5256) * 256 + tid;
    int t = idx >> 8, c = idx & 255;
    wt9[idx] = dw9_w[c * 81 + t];
  } else if (bid < 5346) {               // biases
    int idx = (bid - 5337) * 256 + tid;
    if (idx < 768)
      biasmb[idx] = idx < 256 ? mq_b[idx] * 0.17677669529663689f : mkv_b[idx - 256];
    else if (idx < 1792) {
      int j = idx - 768;
      biaskv[j] = j < 512 ? k_b[j] : v_b[j - 512];
    } else if (idx < 2304) {
      biasq[idx - 1792] = q_b[idx - 1792] * 0.125f;
    }
  } else {                               // tgt cm -> B-frags (1024 blocks)
    int gtid = (bid - 5346) * 256 + tid;
    int l = gtid & 63; int fr = gtid >> 6;
    int kc = fr % 16; int r2 = fr / 16; int nt = r2 & 63; int b = r2 >> 6;
    int lr = l & 15, lu = l >> 4;
    const float* sp = tgt + ((size_t)(b * 512) + kc * 32 + lu * 8) * 1024 + nt * 16 + lr;
    V16u hi, lo;
#pragma unroll
    for (int j = 0; j < 8; ++j) split2(sp[(size_t)j * 1024], hi.u[j], lo.u[j]);
    *(int4*)(tgtfh + (size_t)gtid * 8) = hi.i4;
    *(int4*)(tgtfl + (size_t)gtid * 8) = lo.i4;
  }
}

// ---------------- emb conv via MFMA, split-bf16, 4-way K-split, 16-wide o-tile
// Single-buffer LDS (26 KB) + reg prefetch => 4 blocks/CU, grid 1024 (exact).
__global__ __launch_bounds__(256, 4)
void k_emb_mfma(const ushort* __restrict__ Xt_hi, const ushort* __restrict__ Xt_lo,
                const ushort* __restrict__ Wt_hi, const ushort* __restrict__ Wt_lo,
                float* __restrict__ part) {
  int wgid = (blockIdx.x & 7) * 128 + (blockIdx.x >> 3);
  int yt = wgid & 7;  wgid >>= 3;
  int b  = wgid & 3;  wgid >>= 2;
  int ks = wgid & 3;  wgid >>= 2;
  int mt = wgid;                       // [0,8)
  int tid = threadIdx.x;
  int w = tid >> 6, l = tid & 63;
  int lr = l & 15, lu = l >> 4;
  int y0 = yt * 4;
  int obase = mt * 64 + w * 16;        // one 16-row A-tile per wave

  __shared__ int4 LsH[816];            // 6 padded rows x 34 px x 32 ci bf16
  __shared__ int4 LsL[816];

  int4 gh[4], gl[4];
  int kc0 = ks * 8;

  auto loadstage = [&](int kcg) {
#pragma unroll
    for (int i = 0; i < 4; ++i) {
      int s = tid + 256 * i;
      if (s < 816) {
        int px = s >> 2;
        int u = (s & 3) ^ ((px >> 1) & 3);
        size_t off = ((size_t)(b * 34 + y0) * 34 + px) * 1024 + kcg * 32 + u * 8;
        gh[i] = *(const int4*)(Xt_hi + off);
        gl[i] = *(const int4*)(Xt_lo + off);
      }
    }
  };
  auto writestage = [&]() {
#pragma unroll
    for (int i = 0; i < 4; ++i) {
      int s = tid + 256 * i;
      if (s < 816) { LsH[s] = gh[i]; LsL[s] = gl[i]; }
    }
  };

  f32x4 zero = {0.f, 0.f, 0.f, 0.f};
  f32x4 acc[8];
#pragma unroll
  for (int n = 0; n < 8; ++n) acc[n] = zero;

  loadstage(kc0);
  writestage();

  for (int kc = 0; kc < 8; ++kc) {
    __syncthreads();                   // stage visible to all waves
    if (kc < 7) loadstage(kc0 + kc + 1);   // prefetch next chunk to regs
    int kcg = kc0 + kc;
    const bf16x8* BH = (const bf16x8*)&LsH[0];
    const bf16x8* BL = (const bf16x8*)&LsL[0];
#pragma unroll
    for (int kx = 0; kx < 3; ++kx) {
      bf16x8 bh[12], bl[12];
#pragma unroll
      for (int f = 0; f < 12; ++f) {
        int px = (f >> 1) * 34 + (f & 1) * 16 + kx + lr;
        int idx = px * 4 + (lu ^ ((px >> 1) & 3));
        bh[f] = BH[idx]; bl[f] = BL[idx];
      }
#pragma unroll
      for (int ky = 0; ky < 3; ++ky) {
        int tap = ky * 3 + kx;
        size_t wo = (((size_t)(tap * 512 + obase + lr)) * 1024) + kcg * 32 + lu * 8;
        bf16x8 ah = *(const bf16x8*)(Wt_hi + wo);
        bf16x8 al = *(const bf16x8*)(Wt_lo + wo);
#pragma unroll
        for (int yr = 0; yr < 4; ++yr)
#pragma unroll
          for (int h = 0; h < 2; ++h) {
            int f = (yr + ky) * 2 + h;
            int nf = yr * 2 + h;
            acc[nf] = __builtin_amdgcn_mfma_f32_16x16x32_bf16(ah, bh[f], acc[nf], 0, 0, 0);
            acc[nf] = __builtin_amdgcn_mfma_f32_16x16x32_bf16(ah, bl[f], acc[nf], 0, 0, 0);
            acc[nf] = __builtin_amdgcn_mfma_f32_16x16x32_bf16(al, bh[f], acc[nf], 0, 0, 0);
          }
      }
    }
    if (kc < 7) {
      __syncthreads();                 // all readers done before overwrite
      writestage();
    }
  }

  float* pb = part + (size_t)ks * 2097152;
#pragma unroll
  for (int yr = 0; yr < 4; ++yr)
#pragma unroll
    for (int h = 0; h < 2; ++h) {
      f32x4 c = acc[yr * 2 + h];
      size_t base = ((size_t)(b * 512 + obase + lu * 4)) * 1024
                    + (y0 + yr) * 32 + h * 16 + lr;
#pragma unroll
      for (int r = 0; r < 4; ++r) pb[base + (size_t)r * 1024] = c[r];
    }
}

// ---------------- emb merge: sum 4 parts + bias, write feat_nc (transposing)
__global__ void k_embmerge_nc(const float* __restrict__ part, const float* __restrict__ bias,
                              float* __restrict__ featnc) {
  __shared__ float T[64][65];
  int bid = blockIdx.x;
  int n0 = (bid & 15) << 6; bid >>= 4;
  int c0 = (bid & 3) << 6; int bg = bid >> 2;
  int cl = threadIdx.x & 63, rw = threadIdx.x >> 6;
#pragma unroll
  for (int i = 0; i < 16; ++i) {
    int crow = i * 4 + rw;
    size_t idx = ((size_t)(bg * 256 + c0 + crow)) * 1024 + n0 + cl;
    float v = part[idx] + part[2097152 + idx] + part[4194304 + idx] + part[6291456 + idx];
    T[crow][cl] = v + bias[(bg & 1) * 256 + c0 + crow];
  }
  __syncthreads();
#pragma unroll
  for (int i = 0; i < 16; ++i) {
    int nrow = i * 4 + rw;
    featnc[((size_t)(bg * 1024 + n0 + nrow)) * 256 + c0 + cl] = T[cl][nrow];
  }
}

// ============ generic MFMA GEMM (cm fp32 output) ============
__global__ __launch_bounds__(256)
void k_gemm_mfma(const ushort* __restrict__ Ah, const ushort* __restrict__ Al,
                 const ushort* __restrict__ Bh, const ushort* __restrict__ Bl,
                 const float* __restrict__ bias, float* __restrict__ Y,
                 int KC, int MT, int Mtot) {
  int bid = blockIdx.x;
  int ntb = bid & 15; bid >>= 4;
  int mt = bid % MT; int b = bid / MT;
  int tid = threadIdx.x, w = tid >> 6, l = tid & 63, lr = l & 15, lu = l >> 4;
  int wo = w >> 1, wn = w & 1;
  int ot0 = mt * 4 + wo * 2;
  int nf0 = ntb * 4 + wn * 2;
  const bf16x8* pAh = (const bf16x8*)Ah;
  const bf16x8* pAl = (const bf16x8*)Al;
  const bf16x8* pBh = (const bf16x8*)Bh;
  const bf16x8* pBl = (const bf16x8*)Bl;
  f32x4 zero = {0.f, 0.f, 0.f, 0.f};
  f32x4 acc[2][2];
#pragma unroll
  for (int a = 0; a < 2; ++a)
#pragma unroll
    for (int n = 0; n < 2; ++n) acc[a][n] = zero;
  for (int kc = 0; kc < KC; ++kc) {
    bf16x8 a_h[2], a_l[2];
#pragma unroll
    for (int a = 0; a < 2; ++a) {
      size_t idx = ((size_t)(ot0 + a) * KC + kc) * 64 + l;
      a_h[a] = pAh[idx]; a_l[a] = pAl[idx];
    }
#pragma unroll
    for (int n = 0; n < 2; ++n) {
      size_t idx = (((size_t)(b * 64 + nf0 + n)) * KC + kc) * 64 + l;
      bf16x8 b_h = pBh[idx], b_l = pBl[idx];
#pragma unroll
      for (int a = 0; a < 2; ++a) {
        acc[a][n] = __builtin_amdgcn_mfma_f32_16x16x32_bf16(a_h[a], b_h, acc[a][n], 0, 0, 0);
        acc[a][n] = __builtin_amdgcn_mfma_f32_16x16x32_bf16(a_h[a], b_l, acc[a][n], 0, 0, 0);
        acc[a][n] = __builtin_amdgcn_mfma_f32_16x16x32_bf16(a_l[a], b_h, acc[a][n], 0, 0, 0);
      }
    }
  }
#pragma unroll
  for (int a = 0; a < 2; ++a) {
    int o = (ot0 + a) * 16 + lu * 4;
#pragma unroll
    for (int n = 0; n < 2; ++n) {
      int col = (nf0 + n) * 16 + lr;
#pragma unroll
      for (int r = 0; r < 4; ++r)
        Y[((size_t)(b * Mtot + o + r)) * 1024 + col] = acc[a][n][r] + bias[o + r];
    }
  }
}

// ============ GEMM with token-major residual epilogue (Mtot=256) ============
__global__ __launch_bounds__(256)
void k_gemm_resadd(const ushort* __restrict__ Ah, const ushort* __restrict__ Al,
                   const ushort* __restrict__ Bh, const ushort* __restrict__ Bl,
                   const float* __restrict__ bias, const float* __restrict__ res,
                   float* __restrict__ dst, int KC, int MT, int addmode) {
  int bid = blockIdx.x;
  int ntb = bid & 15; bid >>= 4;
  int mt = bid % MT; int b = bid / MT;
  int tid = threadIdx.x, w = tid >> 6, l = tid & 63, lr = l & 15, lu = l >> 4;
  int wo = w >> 1, wn = w & 1;
  int ot0 = mt * 4 + wo * 2;
  int nf0 = ntb * 4 + wn * 2;
  const bf16x8* pAh = (const bf16x8*)Ah;
  const bf16x8* pAl = (const bf16x8*)Al;
  const bf16x8* pBh = (const bf16x8*)Bh;
  const bf16x8* pBl = (const bf16x8*)Bl;
  f32x4 zero = {0.f, 0.f, 0.f, 0.f};
  f32x4 acc[2][2];
#pragma unroll
  for (int a = 0; a < 2; ++a)
#pragma unroll
    for (int n = 0; n < 2; ++n) acc[a][n] = zero;
  for (int kc = 0; kc < KC; ++kc) {
    bf16x8 a_h[2], a_l[2];
#pragma unroll
    for (int a = 0; a < 2; ++a) {
      size_t idx = ((size_t)(ot0 + a) * KC + kc) * 64 + l;
      a_h[a] = pAh[idx]; a_l[a] = pAl[idx];
    }
#pragma unroll
    for (int n = 0; n < 2; ++n) {
      size_t idx = (((size_t)(b * 64 + nf0 + n)) * KC + kc) * 64 + l;
      bf16x8 b_h = pBh[idx], b_l = pBl[idx];
#pragma unroll
      for (int a = 0; a < 2; ++a) {
        acc[a][n] = __builtin_amdgcn_mfma_f32_16x16x32_bf16(a_h[a], b_h, acc[a][n], 0, 0, 0);
        acc[a][n] = __builtin_amdgcn_mfma_f32_16x16x32_bf16(a_h[a], b_l, acc[a][n], 0, 0, 0);
        acc[a][n] = __builtin_amdgcn_mfma_f32_16x16x32_bf16(a_l[a], b_h, acc[a][n], 0, 0, 0);
      }
    }
  }
#pragma unroll
  for (int a = 0; a < 2; ++a) {
    int o = (ot0 + a) * 16 + lu * 4;
#pragma unroll
    for (int n = 0; n < 2; ++n) {
      int col = (nf0 + n) * 16 + lr;
      size_t addr = ((size_t)((b << 10) + col)) * 256 + o;
      float4 v;
      v.x = acc[a][n][0] + bias[o + 0];
      v.y = acc[a][n][1] + bias[o + 1];
      v.z = acc[a][n][2] + bias[o + 2];
      v.w = acc[a][n][3] + bias[o + 3];
      float4 r4 = addmode ? *(const float4*)(dst + addr) : *(const float4*)(res + addr);
      v.x += r4.x; v.y += r4.y; v.z += r4.z; v.w += r4.w;
      *(float4*)(dst + addr) = v;
    }
  }
}

// ============ GEMM with mb-attention frag epilogue (d=32 heads) ============
__global__ __launch_bounds__(256)
void k_gemm_frag_mb(const ushort* __restrict__ Ah, const ushort* __restrict__ Al,
                    const ushort* __restrict__ Bh, const ushort* __restrict__ Bl,
                    const float* __restrict__ bias,
                    ushort* __restrict__ mQh, ushort* __restrict__ mQl,
                    ushort* __restrict__ mKh, ushort* __restrict__ mKl,
                    ushort* __restrict__ mVh, ushort* __restrict__ mVl) {
  int bid = blockIdx.x;
  int ntb = bid & 15; bid >>= 4;
  int mt = bid % 12; int b = bid / 12;
  int tid = threadIdx.x, w = tid >> 6, l = tid & 63, lr = l & 15, lu = l >> 4;
  int wo = w >> 1, wn = w & 1;
  int ot0 = mt * 4 + wo * 2;
  int nf0 = ntb * 4 + wn * 2;
  const bf16x8* pAh = (const bf16x8*)Ah;
  const bf16x8* pAl = (const bf16x8*)Al;
  const bf16x8* pBh = (const bf16x8*)Bh;
  const bf16x8* pBl = (const bf16x8*)Bl;
  f32x4 zero = {0.f, 0.f, 0.f, 0.f};
  f32x4 acc[2][2];
#pragma unroll
  for (int a = 0; a < 2; ++a)
#pragma unroll
    for (int n = 0; n < 2; ++n) acc[a][n] = zero;
  for (int kc = 0; kc < 8; ++kc) {
    bf16x8 a_h[2], a_l[2];
#pragma unroll
    for (int a = 0; a < 2; ++a) {
      size_t idx = ((size_t)(ot0 + a) * 8 + kc) * 64 + l;
      a_h[a] = pAh[idx]; a_l[a] = pAl[idx];
    }
#pragma unroll
    for (int n = 0; n < 2; ++n) {
      size_t idx = (((size_t)(b * 64 + nf0 + n)) * 8 + kc) * 64 + l;
      bf16x8 b_h = pBh[idx], b_l = pBl[idx];
#pragma unroll
      for (int a = 0; a < 2; ++a) {
        acc[a][n] = __builtin_amdgcn_mfma_f32_16x16x32_bf16(a_h[a], b_h, acc[a][n], 0, 0, 0);
        acc[a][n] = __builtin_amdgcn_mfma_f32_16x16x32_bf16(a_h[a], b_l, acc[a][n], 0, 0, 0);
        acc[a][n] = __builtin_amdgcn_mfma_f32_16x16x32_bf16(a_l[a], b_h, acc[a][n], 0, 0, 0);
      }
    }
  }
#pragma unroll
  for (int a = 0; a < 2; ++a) {
    int o0 = (ot0 + a) * 16 + lu * 4;
#pragma unroll
    for (int n = 0; n < 2; ++n) {
      int col = (nf0 + n) * 16 + lr;
      ushort4 h4, l4;
      split2(acc[a][n][0] + bias[o0 + 0], h4.x, l4.x);
      split2(acc[a][n][1] + bias[o0 + 1], h4.y, l4.y);
      split2(acc[a][n][2] + bias[o0 + 2], h4.z, l4.z);
      split2(acc[a][n][3] + bias[o0 + 3], h4.w, l4.w);
      if (o0 < 512) {
        int oo = o0 & 255;
        int hh = oo >> 5, d = oo & 31;
        ushort* dh = o0 < 256 ? mQh : mKh;
        ushort* dl = o0 < 256 ? mQl : mKl;
        size_t base = ((((size_t)(b * 8 + hh) * 64 + (col >> 4)) * 64)
                       + ((d >> 3) << 4) + (col & 15)) * 8 + (d & 7);
        *(ushort4*)(dh + base) = h4;
        *(ushort4*)(dl + base) = l4;
      } else {
        int oo = o0 - 512;
        int hh = oo >> 5, d = oo & 31;
        int et = d >> 4;
        size_t eb = ((((size_t)((b * 8 + hh) * 2 + et)) * 32 + (col >> 5)) * 64
                     + ((col >> 3) & 3) * 16 + (d & 15)) * 8 + (col & 7);
        mVh[eb] = h4.x; mVh[eb + 8] = h4.y; mVh[eb + 16] = h4.z; mVh[eb + 24] = h4.w;
        mVl[eb] = l4.x; mVl[eb + 8] = l4.y; mVl[eb + 16] = l4.z; mVl[eb + 24] = l4.w;
      }
    }
  }
}

// ============ GEMM with main-attention frag epilogue (d=64 heads) ============
__global__ __launch_bounds__(256)
void k_gemm_frag_main(const ushort* __restrict__ Ah, const ushort* __restrict__ Al,
                      const ushort* __restrict__ Bh, const ushort* __restrict__ Bl,
                      const float* __restrict__ bias,
                      ushort* __restrict__ fh, ushort* __restrict__ fl,
                      ushort* __restrict__ vfh, ushort* __restrict__ vfl,
                      int vbase, int KC, int MT) {
  int bid = blockIdx.x;
  int ntb = bid & 15; bid >>= 4;
  int mt = bid % MT; int b = bid / MT;
  int tid = threadIdx.x, w = tid >> 6, l = tid & 63, lr = l & 15, lu = l >> 4;
  int wo = w >> 1, wn = w & 1;
  int ot0 = mt * 4 + wo * 2;
  int nf0 = ntb * 4 + wn * 2;
  const bf16x8* pAh = (const bf16x8*)Ah;
  const bf16x8* pAl = (const bf16x8*)Al;
  const bf16x8* pBh = (const bf16x8*)Bh;
  const bf16x8* pBl = (const bf16x8*)Bl;
  f32x4 zero = {0.f, 0.f, 0.f, 0.f};
  f32x4 acc[2][2];
#pragma unroll
  for (int a = 0; a < 2; ++a)
#pragma unroll
    for (int n = 0; n < 2; ++n) acc[a][n] = zero;
  for (int kc = 0; kc < KC; ++kc) {
    bf16x8 a_h[2], a_l[2];
#pragma unroll
    for (int a = 0; a < 2; ++a) {
      size_t idx = ((size_t)(ot0 + a) * KC + kc) * 64 + l;
      a_h[a] = pAh[idx]; a_l[a] = pAl[idx];
    }
#pragma unroll
    for (int n = 0; n < 2; ++n) {
      size_t idx = (((size_t)(b * 64 + nf0 + n)) * KC + kc) * 64 + l;
      bf16x8 b_h = pBh[idx], b_l = pBl[idx];
#pragma unroll
      for (int a = 0; a < 2; ++a) {
        acc[a][n] = __builtin_amdgcn_mfma_f32_16x16x32_bf16(a_h[a], b_h, acc[a][n], 0, 0, 0);
        acc[a][n] = __builtin_amdgcn_mfma_f32_16x16x32_bf16(a_h[a], b_l, acc[a][n], 0, 0, 0);
        acc[a][n] = __builtin_amdgcn_mfma_f32_16x16x32_bf16(a_l[a], b_h, acc[a][n], 0, 0, 0);
      }
    }
  }
#pragma unroll
  for (int a = 0; a < 2; ++a) {
    int o0 = (ot0 + a) * 16 + lu * 4;
#pragma unroll
    for (int n = 0; n < 2; ++n) {
      int col = (nf0 + n) * 16 + lr;
      ushort4 h4, l4;
      split2(acc[a][n][0] + bias[o0 + 0], h4.x, l4.x);
      split2(acc[a][n][1] + bias[o0 + 1], h4.y, l4.y);
      split2(acc[a][n][2] + bias[o0 + 2], h4.z, l4.z);
      split2(acc[a][n][3] + bias[o0 + 3], h4.w, l4.w);
      if (o0 < vbase) {
        int h = o0 >> 6, d = o0 & 63;
        int dc = d >> 5;
        size_t base = (((((size_t)(b * 8 + h) * 64 + (col >> 4)) * 2 + dc) * 64)
                       + (((d & 31) >> 3) << 4) + (col & 15)) * 8 + (d & 7);
        *(ushort4*)(fh + base) = h4;
        *(ushort4*)(fl + base) = l4;
      } else {
        int oo = o0 - vbase;
        int h = oo >> 6, d = oo & 63;
        int et = d >> 4;
        size_t eb = ((((size_t)((b * 8 + h) * 4 + et)) * 32 + (col >> 5)) * 64
                     + ((col >> 3) & 3) * 16 + (d & 15)) * 8 + (col & 7);
        vfh[eb] = h4.x; vfh[eb + 8] = h4.y; vfh[eb + 16] = h4.z; vfh[eb + 24] = h4.w;
        vfl[eb] = l4.x; vfl[eb + 8] = l4.y; vfl[eb + 16] = l4.z; vfl[eb + 24] = l4.w;
      }
    }
  }
}

// ---------------- FUSED ln1 (->xbuf) + n1 (->B-frags), wave per token
__global__ void k_ln1n1(const float* __restrict__ featnc,
                        const float* __restrict__ g1, const float* __restrict__ b1,
                        const float* __restrict__ gn, const float* __restrict__ bn,
                        float* __restrict__ xbuf,
                        ushort* __restrict__ dh, ushort* __restrict__ dl) {
  int token = (blockIdx.x * 256 + threadIdx.x) >> 6;
  int lane = threadIdx.x & 63;
  float4 v4 = *reinterpret_cast<const float4*>(featnc + (size_t)token * 256 + lane * 4);
  float s  = v4.x + v4.y + v4.z + v4.w;
  float s2 = v4.x * v4.x + v4.y * v4.y + v4.z * v4.z + v4.w * v4.w;
#pragma unroll
  for (int off = 32; off; off >>= 1) { s += __shfl_xor(s, off); s2 += __shfl_xor(s2, off); }
  float mean = s * (1.f / 256.f);
  float rstd = rsqrtf(s2 * (1.f / 256.f) - mean * mean + 1e-5f);
  float4 g4 = *reinterpret_cast<const float4*>(g1 + lane * 4);
  float4 b4 = *reinterpret_cast<const float4*>(b1 + lane * 4);
  float4 x;
  x.x = (v4.x - mean) * rstd * g4.x + b4.x;
  x.y = (v4.y - mean) * rstd * g4.y + b4.y;
  x.z = (v4.z - mean) * rstd * g4.z + b4.z;
  x.w = (v4.w - mean) * rstd * g4.w + b4.w;
  *reinterpret_cast<float4*>(xbuf + (size_t)token * 256 + lane * 4) = x;
  float t  = x.x + x.y + x.z + x.w;
  float t2 = x.x * x.x + x.y * x.y + x.z * x.z + x.w * x.w;
#pragma unroll
  for (int off = 32; off; off >>= 1) { t += __shfl_xor(t, off); t2 += __shfl_xor(t2, off); }
  float mean2 = t * (1.f / 256.f);
  float rstd2 = rsqrtf(t2 * (1.f / 256.f) - mean2 * mean2 + 1e-6f);
  float4 gg = *reinterpret_cast<const float4*>(gn + lane * 4);
  float4 bb = *reinterpret_cast<const float4*>(bn + lane * 4);
  ushort4 h4, l4;
  split2((x.x - mean2) * rstd2 * gg.x + bb.x, h4.x, l4.x);
  split2((x.y - mean2) * rstd2 * gg.y + bb.y, h4.y, l4.y);
  split2((x.z - mean2) * rstd2 * gg.z + bb.z, h4.z, l4.z);
  split2((x.w - mean2) * rstd2 * gg.w + bb.w, h4.w, l4.w);
  int bg = token >> 10, nt = (token >> 4) & 63, lr = token & 15;
  int kc = lane >> 3, lu_f = (lane >> 1) & 3, j0 = (lane & 1) * 4;
  size_t base = ((((size_t)(bg * 64 + nt)) * 8 + kc) * 64 + lu_f * 16 + lr) * 8 + j0;
  *(ushort4*)(dh + base) = h4;
  *(ushort4*)(dl + base) = l4;
}

// ---------------- token-major LN -> B-frags (KC=8), standalone (n2)
__global__ void k_ln_frag(const float* __restrict__ xin, const float* __restrict__ g_,
                          const float* __restrict__ b_, ushort* __restrict__ dh,
                          ushort* __restrict__ dl, float eps) {
  int token = (blockIdx.x * 256 + threadIdx.x) >> 6;
  int lane = threadIdx.x & 63;
  float4 v4 = *reinterpret_cast<const float4*>(xin + (size_t)token * 256 + lane * 4);
  float s  = v4.x + v4.y + v4.z + v4.w;
  float s2 = v4.x * v4.x + v4.y * v4.y + v4.z * v4.z + v4.w * v4.w;
#pragma unroll
  for (int off = 32; off; off >>= 1) { s += __shfl_xor(s, off); s2 += __shfl_xor(s2, off); }
  float mean = s * (1.f / 256.f);
  float rstd = rsqrtf(s2 * (1.f / 256.f) - mean * mean + eps);
  float4 g4 = *reinterpret_cast<const float4*>(g_ + lane * 4);
  float4 b4 = *reinterpret_cast<const float4*>(b_ + lane * 4);
  ushort4 h4, l4;
  split2((v4.x - mean) * rstd * g4.x + b4.x, h4.x, l4.x);
  split2((v4.y - mean) * rstd * g4.y + b4.y, h4.y, l4.y);
  split2((v4.z - mean) * rstd * g4.z + b4.z, h4.z, l4.z);
  split2((v4.w - mean) * rstd * g4.w + b4.w, h4.w, l4.w);
  int bg = token >> 10, nt = (token >> 4) & 63, lr = token & 15;
  int kc = lane >> 3, lu_f = (lane >> 1) & 3, j0 = (lane & 1) * 4;
  size_t base = ((((size_t)(bg * 64 + nt)) * 8 + kc) * 64 + lu_f * 16 + lr) * 8 + j0;
  *(ushort4*)(dh + base) = h4;
  *(ushort4*)(dl + base) = l4;
}

// ============ MitBlock attention (MFMA, d=32), epilogue -> B-frags ============
__global__ __launch_bounds__(256)
void k_mbattn_mfma(const ushort* __restrict__ Qh, const ushort* __restrict__ Ql,
                   const ushort* __restrict__ Kh, const ushort* __restrict__ Kl,
                   const ushort* __restrict__ Vh, const ushort* __restrict__ Vl,
                   ushort* __restrict__ ofh, ushort* __restrict__ ofl) {
  int qb = blockIdx.x & 15, bgh = blockIdx.x >> 4;
  int tid = threadIdx.x, w = tid >> 6, l = tid & 63, lr = l & 15, lu = l >> 4;
  int qt = qb * 4 + w;
  bf16x8 qh = ((const bf16x8*)Qh)[(size_t)(bgh * 64 + qt) * 64 + l];
  bf16x8 ql = ((const bf16x8*)Ql)[(size_t)(bgh * 64 + qt) * 64 + l];
  __shared__ ushort Ph[4][16][72];
  __shared__ ushort Pl[4][16][72];
  f32x4 zero = {0.f, 0.f, 0.f, 0.f};
  f32x4 oacc[2] = {zero, zero};
  float den = 0.f;
  for (int kb = 0; kb < 16; ++kb) {
#pragma unroll
    for (int kt4 = 0; kt4 < 4; ++kt4) {
      int kt = kb * 4 + kt4;
      bf16x8 kh = ((const bf16x8*)Kh)[(size_t)(bgh * 64 + kt) * 64 + l];
      bf16x8 kl = ((const bf16x8*)Kl)[(size_t)(bgh * 64 + kt) * 64 + l];
      f32x4 s = zero;
      s = __builtin_amdgcn_mfma_f32_16x16x32_bf16(kh, qh, s, 0, 0, 0);
      s = __builtin_amdgcn_mfma_f32_16x16x32_bf16(kh, ql, s, 0, 0, 0);
      s = __builtin_amdgcn_mfma_f32_16x16x32_bf16(kl, qh, s, 0, 0, 0);
      uint2 uh, ul;
      {
        float p0 = __expf(s[0]), p1 = __expf(s[1]), p2 = __expf(s[2]), p3 = __expf(s[3]);
        den += (p0 + p1) + (p2 + p3);
        ushort h0, l0, h1, l1, h2, l2, h3, l3;
        split2(p0, h0, l0); split2(p1, h1, l1); split2(p2, h2, l2); split2(p3, h3, l3);
        uh.x = (unsigned)h0 | ((unsigned)h1 << 16); uh.y = (unsigned)h2 | ((unsigned)h3 << 16);
        ul.x = (unsigned)l0 | ((unsigned)l1 << 16); ul.y = (unsigned)l2 | ((unsigned)l3 << 16);
      }
      *(uint2*)&Ph[w][lr][kt4 * 16 + lu * 4] = uh;
      *(uint2*)&Pl[w][lr][kt4 * 16 + lu * 4] = ul;
    }
#pragma unroll
    for (int kc2 = 0; kc2 < 2; ++kc2) {
      int kc = kb * 2 + kc2;
      bf16x8 bph = *(const bf16x8*)&Ph[w][lr][kc2 * 32 + lu * 8];
      bf16x8 bpl = *(const bf16x8*)&Pl[w][lr][kc2 * 32 + lu * 8];
#pragma unroll
      for (int et = 0; et < 2; ++et) {
        bf16x8 vh = ((const bf16x8*)Vh)[(size_t)((bgh * 2 + et) * 32 + kc) * 64 + l];
        bf16x8 vl = ((const bf16x8*)Vl)[(size_t)((bgh * 2 + et) * 32 + kc) * 64 + l];
        oacc[et] = __builtin_amdgcn_mfma_f32_16x16x32_bf16(vh, bph, oacc[et], 0, 0, 0);
        oacc[et] = __builtin_amdgcn_mfma_f32_16x16x32_bf16(vh, bpl, oacc[et], 0, 0, 0);
        oacc[et] = __builtin_amdgcn_mfma_f32_16x16x32_bf16(vl, bph, oacc[et], 0, 0, 0);
      }
    }
  }
  den += __shfl_xor(den, 16);
  den += __shfl_xor(den, 32);
  float inv = 1.f / den;
  int bg = bgh >> 3, hh = bgh & 7;
#pragma unroll
  for (int et = 0; et < 2; ++et) {
    ushort4 h4, l4;
    split2(oacc[et][0] * inv, h4.x, l4.x); split2(oacc[et][1] * inv, h4.y, l4.y);
    split2(oacc[et][2] * inv, h4.z, l4.z); split2(oacc[et][3] * inv, h4.w, l4.w);
    int lu_f = et * 2 + (lu >> 1), j0 = (lu & 1) * 4;
    size_t base = ((((size_t)(bg * 64 + qt)) * 8 + hh) * 64 + lu_f * 16 + lr) * 8 + j0;
    *(ushort4*)(ofh + base) = h4;
    *(ushort4*)(ofl + base) = l4;
  }
}

// ============ main attention (MFMA, d=64), epilogue -> B-frags (KC=16) ========
__global__ __launch_bounds__(256)
void k_mainattn_mfma(const ushort* __restrict__ Qh, const ushort* __restrict__ Ql,
                     const ushort* __restrict__ Kh, const ushort* __restrict__ Kl,
                     const ushort* __restrict__ Vh, const ushort* __restrict__ Vl,
                     ushort* __restrict__ anfh, ushort* __restrict__ anfl) {
  int qb = blockIdx.x & 15, bh = blockIdx.x >> 4;
  int tid = threadIdx.x, w = tid >> 6, l = tid & 63, lr = l & 15, lu = l >> 4;
  int qt = qb * 4 + w;
  bf16x8 qh[2], ql[2];
#pragma unroll
  for (int dc = 0; dc < 2; ++dc) {
    qh[dc] = ((const bf16x8*)Qh)[(size_t)((bh * 64 + qt) * 2 + dc) * 64 + l];
    ql[dc] = ((const bf16x8*)Ql)[(size_t)((bh * 64 + qt) * 2 + dc) * 64 + l];
  }
  __shared__ ushort Ph[4][16][72];
  __shared__ ushort Pl[4][16][72];
  f32x4 zero = {0.f, 0.f, 0.f, 0.f};
  f32x4 oacc[4] = {zero, zero, zero, zero};
  float den = 0.f;
  for (int kb = 0; kb < 16; ++kb) {
#pragma unroll
    for (int kt4 = 0; kt4 < 4; ++kt4) {
      int kt = kb * 4 + kt4;
      f32x4 s = zero;
#pragma unroll
      for (int dc = 0; dc < 2; ++dc) {
        bf16x8 kh = ((const bf16x8*)Kh)[(size_t)((bh * 64 + kt) * 2 + dc) * 64 + l];
        bf16x8 kl = ((const bf16x8*)Kl)[(size_t)((bh * 64 + kt) * 2 + dc) * 64 + l];
        s = __builtin_amdgcn_mfma_f32_16x16x32_bf16(kh, qh[dc], s, 0, 0, 0);
        s = __builtin_amdgcn_mfma_f32_16x16x32_bf16(kh, ql[dc], s, 0, 0, 0);
        s = __builtin_amdgcn_mfma_f32_16x16x32_bf16(kl, qh[dc], s, 0, 0, 0);
      }
      uint2 uh, ul;
      {
        float p0 = __expf(s[0]), p1 = __expf(s[1]), p2 = __expf(s[2]), p3 = __expf(s[3]);
        den += (p0 + p1) + (p2 + p3);
        ushort h0, l0, h1, l1, h2, l2, h3, l3;
        split2(p0, h0, l0); split2(p1, h1, l1); split2(p2, h2, l2); split2(p3, h3, l3);
        uh.x = (unsigned)h0 | ((unsigned)h1 << 16); uh.y = (unsigned)h2 | ((unsigned)h3 << 16);
        ul.x = (unsigned)l0 | ((unsigned)l1 << 16); ul.y = (unsigned)l2 | ((unsigned)l3 << 16);
      }
      *(uint2*)&Ph[w][lr][kt4 * 16 + lu * 4] = uh;
      *(uint2*)&Pl[w][lr][kt4 * 16 + lu * 4] = ul;
    }
#pragma unroll
    for (int kc2 = 0; kc2 < 2; ++kc2) {
      int kc = kb * 2 + kc2;
      bf16x8 bph = *(const bf16x8*)&Ph[w][lr][kc2 * 32 + lu * 8];
      bf16x8 bpl = *(const bf16x8*)&Pl[w][lr][kc2 * 32 + lu * 8];
#pragma unroll
      for (int et = 0; et < 4; ++et) {
        bf16x8 vh = ((const bf16x8*)Vh)[(size_t)((bh * 4 + et) * 32 + kc) * 64 + l];
        bf16x8 vl = ((const bf16x8*)Vl)[(size_t)((bh * 4 + et) * 32 + kc) * 64 + l];
        oacc[et] = __builtin_amdgcn_mfma_f32_16x16x32_bf16(vh, bph, oacc[et], 0, 0, 0);
        oacc[et] = __builtin_amdgcn_mfma_f32_16x16x32_bf16(vh, bpl, oacc[et], 0, 0, 0);
        oacc[et] = __builtin_amdgcn_mfma_f32_16x16x32_bf16(vl, bph, oacc[et], 0, 0, 0);
      }
    }
  }
  den += __shfl_xor(den, 16);
  den += __shfl_xor(den, 32);
  float inv = 1.f / den;
  int b = bh >> 3, h = bh & 7;
#pragma unroll
  for (int et = 0; et < 4; ++et) {
    ushort4 h4, l4;
    split2(oacc[et][0] * inv, h4.x, l4.x); split2(oacc[et][1] * inv, h4.y, l4.y);
    split2(oacc[et][2] * inv, h4.z, l4.z); split2(oacc[et][3] * inv, h4.w, l4.w);
    int kc = h * 2 + (et >> 1);
    int lu_f = (et & 1) * 2 + (lu >> 1), j0 = (lu & 1) * 4;
    size_t base = ((((size_t)(b * 64 + qt)) * 16 + kc) * 64 + lu_f * 16 + lr) * 8 + j0;
    *(ushort4*)(anfh + base) = h4;
    *(ushort4*)(anfl + base) = l4;
  }
}

// ---------------- FUSED dw3 + GELU -> fc2 B-frags directly
__global__ void k_dw3_frag(const float* __restrict__ X, const float* __restrict__ w,
                           const float* __restrict__ bias,
                           ushort* __restrict__ dh, ushort* __restrict__ dl) {
  int bid = blockIdx.x;               // 4096 = bg(8) x chg(128) x pch(4)
  int pch = bid & 3; bid >>= 2;
  int chg = bid & 127; int bg = bid >> 7;
  int tid = threadIdx.x;
  int n = pch * 256 + tid;
  int x = n & 31, y = n >> 5;
  int ch0 = chg * 8;
  V16u hi, lo;
#pragma unroll
  for (int jj = 0; jj < 8; ++jj) {
    int ch = ch0 + jj;
    const float* src = X + ((size_t)((bg << 10) + ch)) * HW;
    const float* wr = w + ch * 9;
    float acc = bias[ch];
#pragma unroll
    for (int ky = 0; ky < 3; ++ky) {
      int yy = y + ky - 1;
      if ((unsigned)yy < 32u) {
        const float* row = src + yy * 32;
#pragma unroll
        for (int kx = 0; kx < 3; ++kx) {
          int xx = x + kx - 1;
          if ((unsigned)xx < 32u) acc += row[xx] * wr[ky * 3 + kx];
        }
      }
    }
    split2(gelu_exact(acc), hi.u[jj], lo.u[jj]);
  }
  size_t base = ((((size_t)(bg * 64 + (n >> 4)) * 32 + (ch0 >> 5)) * 64)
                 + ((ch0 >> 3) & 3) * 16 + (n & 15)) * 8;
  *(int4*)(dh + base) = hi.i4;
  *(int4*)(dl + base) = lo.i4;
}

// ---------------- FUSED depthwise 9x9 + LN + GELU + [2,256] proj + tanh -> pos
// Block = 8 pixels x 256 channels; LN/proj reductions done in-block.
__global__ void k_dw9cotail(const float* __restrict__ Xnc, const float* __restrict__ wt9,
                            const float* __restrict__ bias,
                            const float* __restrict__ lnw, const float* __restrict__ lnb,
                            const float* __restrict__ w2, float* __restrict__ pos) {
  int bid = blockIdx.x;               // 1024 = bg(8) x ptile(128)
  int pt = bid & 127; int bg = bid >> 7;
  int tid = threadIdx.x;              // = channel
  int y = pt >> 2, x0 = (pt & 3) * 8;
  float acc[8];
  float bs = bias[tid];
#pragma unroll
  for (int p = 0; p < 8; ++p) acc[p] = bs;
  const float* src = Xnc + (size_t)(bg << 10) * 256;
  for (int ky = 0; ky < 9; ++ky) {
    int yy = y + ky - 4;
    if ((unsigned)yy >= 32u) continue;
#pragma unroll
    for (int kx = 0; kx < 9; ++kx) {
      float wv = wt9[(ky * 9 + kx) * 256 + tid];
#pragma unroll
      for (int p = 0; p < 8; ++p) {
        int xx = x0 + p + kx - 4;
        if ((unsigned)xx < 32u)
          acc[p] += src[(size_t)(yy * 32 + xx) * 256 + tid] * wv;
      }
    }
  }
  // --- cotail: per-pixel LN over 256 channels + GELU + proj + tanh ---
  __shared__ float rs[8][4], rs2[8][4], ro0[8][4], ro1[8][4];
  int wv = tid >> 6, ln = tid & 63;
  float lw = lnw[tid], lb = lnb[tid];
  float wa = w2[tid], wb = w2[256 + tid];
#pragma unroll
  for (int p = 0; p < 8; ++p) {
    float a = acc[p], b2 = acc[p] * acc[p];
#pragma unroll
    for (int off = 32; off; off >>= 1) { a += __shfl_xor(a, off); b2 += __shfl_xor(b2, off); }
    if (ln == 0) { rs[p][wv] = a; rs2[p][wv] = b2; }
  }
  __syncthreads();
#pragma unroll
  for (int p = 0; p < 8; ++p) {
    float tot  = rs[p][0] + rs[p][1] + rs[p][2] + rs[p][3];
    float tot2 = rs2[p][0] + rs2[p][1] + rs2[p][2] + rs2[p][3];
    float mean = tot * (1.f / 256.f);
    float rstd = rsqrtf(tot2 * (1.f / 256.f) - mean * mean + 1e-5f);
    float ge = gelu_exact((acc[p] - mean) * rstd * lw + lb);
    float o0 = ge * wa, o1 = ge * wb;
#pragma unroll
    for (int off = 32; off; off >>= 1) { o0 += __shfl_xor(o0, off); o1 += __shfl_xor(o1, off); }
    if (ln == 0) { ro0[p][wv] = o0; ro1[p][wv] = o1; }
  }
  __syncthreads();
  if (tid < 8) {
    int p = tid;
    float o0 = ro0[p][0] + ro0[p][1] + ro0[p][2] + ro0[p][3];
    float o1 = ro1[p][0] + ro1[p][1] + ro1[p][2] + ro1[p][3];
    float offy = tanhf(o0) * (2.f / 32.f);
    float offx = tanhf(o1) * (2.f / 32.f);
    int n = y * 32 + x0 + p;
    float refy = ((y + 0.5f) * (1.f / 32.f)) * 2.f - 1.f;
    float refx = ((x0 + p + 0.5f) * (1.f / 32.f)) * 2.f - 1.f;
    pos[((bg << 10) + n) * 2]     = offx + refx;
    pos[((bg << 10) + n) * 2 + 1] = offy + refy;
  }
}

// ---------------- FUSED bilinear grid sample -> kv-GEMM B-frags directly
__global__ void k_gsample_frag(const float* __restrict__ Xnc, const float* __restrict__ pos,
                               ushort* __restrict__ dh, ushort* __restrict__ dl) {
  int bid = blockIdx.x;               // 128 = bg(8) x nch(16)
  int nch = bid & 15; int bg = bid >> 4;
  int tid = threadIdx.x;              // channel c [0,256)
  __shared__ int sI[4][64];
  __shared__ float sW[4][64];
  if (tid < 64) {
    int j = nch * 64 + tid;
    float gx = pos[((bg << 10) + j) * 2];
    float gy = pos[((bg << 10) + j) * 2 + 1];
    float fx = (gx + 1.f) * 0.5f * 31.f;
    float fy = (gy + 1.f) * 0.5f * 31.f;
    float x0f = floorf(fx), y0f = floorf(fy);
    int x0 = (int)x0f, y0 = (int)y0f;
    float wx1 = fx - x0f, wx0 = 1.f - wx1;
    float wy1 = fy - y0f, wy0 = 1.f - wy1;
    bool vx0 = (x0 >= 0) & (x0 <= 31);
    bool vx1 = (x0 + 1 >= 0) & (x0 + 1 <= 31);
    bool vy0 = (y0 >= 0) & (y0 <= 31);
    bool vy1 = (y0 + 1 >= 0) & (y0 + 1 <= 31);
    int cx0 = min(max(x0, 0), 31), cx1 = min(max(x0 + 1, 0), 31);
    int cy0 = min(max(y0, 0), 31), cy1 = min(max(y0 + 1, 0), 31);
    sW[0][tid] = wx0 * wy0 * ((vx0 && vy0) ? 1.f : 0.f);
    sW[1][tid] = wx1 * wy0 * ((vx1 && vy0) ? 1.f : 0.f);
    sW[2][tid] = wx0 * wy1 * ((vx0 && vy1) ? 1.f : 0.f);
    sW[3][tid] = wx1 * wy1 * ((vx1 && vy1) ? 1.f : 0.f);
    sI[0][tid] = cy0 * 32 + cx0; sI[1][tid] = cy0 * 32 + cx1;
    sI[2][tid] = cy1 * 32 + cx0; sI[3][tid] = cy1 * 32 + cx1;
  }
  __syncthreads();
  int b = bg >> 1, g = bg & 1;
  const float* src = Xnc + (size_t)(bg << 10) * 256;
  for (int nn = 0; nn < 64; ++nn) {
    float acc = src[(size_t)sI[0][nn] * 256 + tid] * sW[0][nn]
              + src[(size_t)sI[1][nn] * 256 + tid] * sW[1][nn]
              + src[(size_t)sI[2][nn] * 256 + tid] * sW[2][nn]
              + src[(size_t)sI[3][nn] * 256 + tid] * sW[3][nn];
    ushort h, l; split2(acc, h, l);
    int jglob = nch * 64 + nn;
    size_t addr = ((((size_t)(b * 64 + (jglob >> 4)) * 16) + g * 8 + (tid >> 5)) * 64
                   + ((tid >> 3) & 3) * 16 + (jglob & 15)) * 8 + (tid & 7);
    dh[addr] = h; dl[addr] = l;
  }
}

// ---------------------------------------------------------------------------
extern "C" void kernel_launch(void* const* d_in, const int* in_sizes, int n_in,
                              void* d_out, int out_size, void* d_ws, size_t ws_size,
                              hipStream_t stream) {
  const float* tgt    = (const float*)d_in[0];
  const float* refp   = (const float*)d_in[1];
  const float* emb_w  = (const float*)d_in[2];
  const float* emb_b  = (const float*)d_in[3];
  const float* q_w    = (const float*)d_in[4];
  const float* q_b    = (const float*)d_in[5];
  const float* k_w    = (const float*)d_in[6];
  const float* k_b    = (const float*)d_in[7];
  const float* v_w    = (const float*)d_in[8];
  const float* v_b    = (const float*)d_in[9];
  const float* out_w  = (const float*)d_in[10];
  const float* out_b  = (const float*)d_in[11];
  const float* ln1_w  = (const float*)d_in[12];
  const float* ln1_b  = (const float*)d_in[13];
  const float* n1_w   = (const float*)d_in[14];
  const float* n1_b   = (const float*)d_in[15];
  const float* mbq_w  = (const float*)d_in[16];
  const float* mbq_b  = (const float*)d_in[17];
  const float* mbkv_w = (const float*)d_in[18];
  const float* mbkv_b = (const float*)d_in[19];
  const float* mbp_w  = (const float*)d_in[20];
  const float* mbp_b  = (const float*)d_in[21];
  const float* n2_w   = (const float*)d_in[22];
  const float* n2_b   = (const float*)d_in[23];
  const float* fc1_w  = (const float*)d_in[24];
  const float* fc1_b  = (const float*)d_in[25];
  const float* dw3_w  = (const float*)d_in[26];
  const float* dw3_b  = (const float*)d_in[27];
  const float* fc2_w  = (const float*)d_in[28];
  const float* fc2_b  = (const float*)d_in[29];
  const float* dw9_w  = (const float*)d_in[30];
  const float* dw9_b  = (const float*)d_in[31];
  const float* coln_w = (const float*)d_in[32];
  const float* coln_b = (const float*)d_in[33];
  const float* coout_w= (const float*)d_in[34];

  float* ws = (float*)d_ws;
  float* slabA = ws + 0;
  float* qfrag = ws + 2097152;
  float* xbuf  = ws + 4194304;
  float* slabF = ws + 10485760;
  float* slabG = ws + 14680064;
  float* slabH = ws + 23068672;
  float* featnc= ws + 31457280;
  float* posb  = ws + 35389440;
  float* wt9   = ws + 35405824;
  float* biasmb= ws + 35426560;
  float* biaskv= ws + 35427328;
  float* biasq = ws + 35428352;

  ushort* XtH = (ushort*)(ws + 4194304);
  ushort* XtL = XtH + 4734976;
  ushort* WtEH = (ushort*)slabG;
  ushort* WtEL = WtEH + 4718592;
  float* part = slabH;
  ushort* tgtfh = (ushort*)slabF;
  ushort* tgtfl = tgtfh + 2097152;

  // weight frags (slab J)
  ushort* J = (ushort*)(ws + 33554432);
  ushort* wfq_h   = J;                ushort* wfq_l   = J + 262144;
  ushort* wfkv_h  = J + 524288;       ushort* wfkv_l  = J + 1048576;
  ushort* wfo_h   = J + 1572864;      ushort* wfo_l   = J + 1835008;
  ushort* wfmqkv_h= J + 2097152;      ushort* wfmqkv_l= J + 2293760;
  ushort* wfmp_h  = J + 2490368;      ushort* wfmp_l  = J + 2555904;
  ushort* wff1_h  = J + 2621440;      ushort* wff1_l  = J + 2883584;
  ushort* wff2_h  = J + 3145728;      ushort* wff2_l  = J + 3407872;

  // phase pointers
  ushort* hfh = (ushort*)slabH;     ushort* hfl = hfh + 2097152;   // n1 frags (part dead)
  ushort* mQh = (ushort*)slabG;     ushort* mQl = mQh + 2097152;
  ushort* mKh = mQh + 4194304;      ushort* mKl = mQh + 6291456;
  ushort* mVh = mQh + 8388608;      ushort* mVl = mQh + 10485760;
  ushort* ofh = (ushort*)slabF;     ushort* ofl = ofh + 2097152;   // mb out frags
  ushort* h2fh = (ushort*)slabF;    ushort* h2fl = h2fh + 2097152;
  float* m_cm = slabG;
  ushort* mifh = (ushort*)slabH;    ushort* mifl = mifh + 8388608;
  float* offin = slabA;
  ushort* sfh = (ushort*)slabF;     ushort* sfl = sfh + 2097152;
  ushort* aQh = (ushort*)qfrag;     ushort* aQl = aQh + 2097152;
  ushort* aKh = (ushort*)slabG;     ushort* aKl = aKh + 2097152;
  ushort* aVh = aKh + 4194304;      ushort* aVl = aKh + 6291456;
  ushort* anfh = (ushort*)slabH;    ushort* anfl = anfh + 2097152;

  // --- step 0: mega-prep (incl. tgt frags) ---
  k_prep_all<<<6370, 256, 0, stream>>>(
      emb_w, tgt, refp, q_w, k_w, v_w, out_w, mbq_w, mbkv_w, mbp_w, fc1_w, fc2_w,
      dw9_w, q_b, mbq_b, mbkv_b, k_b, v_b,
      WtEH, WtEL, XtH, XtL,
      wfq_h, wfq_l, wfkv_h, wfkv_l, wfo_h, wfo_l, wfmqkv_h, wfmqkv_l,
      wfmp_h, wfmp_l, wff1_h, wff1_l, wff2_h, wff2_l,
      wt9, biasmb, biaskv, biasq, tgtfh, tgtfl);
  // --- step 1: emb conv (16-wide o-tile, 4 blocks/CU) + merge ---
  k_emb_mfma<<<1024, 256, 0, stream>>>(XtH, XtL, WtEH, WtEL, part);
  k_embmerge_nc<<<512, 256, 0, stream>>>(part, emb_b, featnc);
  // --- step 2: q proj -> main Q frags directly (scale folded) ---
  k_gemm_frag_main<<<512, 256, 0, stream>>>(wfq_h, wfq_l, tgtfh, tgtfl, biasq,
                                            aQh, aQl, aVh, aVl, 512, 16, 8);
  // --- step 3+4: fused ln1 -> xbuf + n1 -> frags (slabH) ---
  k_ln1n1<<<2048, 256, 0, stream>>>(featnc, ln1_w, ln1_b, n1_w, n1_b, xbuf, hfh, hfl);
  // --- step 5+6a: mqkv GEMM -> mb Q/K/V frags directly ---
  k_gemm_frag_mb<<<1536, 256, 0, stream>>>(wfmqkv_h, wfmqkv_l, hfh, hfl, biasmb,
                                           mQh, mQl, mKh, mKl, mVh, mVl);
  // --- step 6: mb attention ---
  k_mbattn_mfma<<<1024, 256, 0, stream>>>(mQh, mQl, mKh, mKl, mVh, mVl, ofh, ofl);
  // --- step 7: mbproj GEMM + residual-add into xbuf (fused) ---
  k_gemm_resadd<<<512, 256, 0, stream>>>(wfmp_h, wfmp_l, ofh, ofl, mbp_b,
                                         xbuf, xbuf, 8, 4, 1);
  // --- step 8: n2 -> h2 frags ---
  k_ln_frag<<<2048, 256, 0, stream>>>(xbuf, n2_w, n2_b, h2fh, h2fl, 1e-6f);
  // --- step 9: fc1 -> m_cm (slabG) ---
  k_gemm_mfma<<<2048, 256, 0, stream>>>(wff1_h, wff1_l, h2fh, h2fl, fc1_b, m_cm, 8, 16, 1024);
  // --- step 10: dw3 + gelu -> fc2 B-frags directly (slabH) ---
  k_dw3_frag<<<4096, 256, 0, stream>>>(m_cm, dw3_w, dw3_b, mifh, mifl);
  // --- step 11: fc2 GEMM + residual -> offin nc (fused) ---
  k_gemm_resadd<<<512, 256, 0, stream>>>(wff2_h, wff2_l, mifh, mifl, fc2_b,
                                         xbuf, offin, 32, 4, 0);
  // --- step 12+13: dw9 + cotail fused -> pos ---
  k_dw9cotail<<<1024, 256, 0, stream>>>(offin, wt9, dw9_b, coln_w, coln_b, coout_w, posb);
  // --- step 14+15a: grid sample -> kv B-frags directly (slabF) ---
  k_gsample_frag<<<128, 256, 0, stream>>>(featnc, posb, sfh, sfl);
  // --- step 15+16a: k+v GEMM -> main K frags + V^T frags directly ---
  k_gemm_frag_main<<<1024, 256, 0, stream>>>(wfkv_h, wfkv_l, sfh, sfl, biaskv,
                                             aKh, aKl, aVh, aVl, 512, 16, 16);
  // --- step 16: main attention ---
  k_mainattn_mfma<<<512, 256, 0, stream>>>(aQh, aQl, aKh, aKl, aVh, aVl, anfh, anfl);
  // --- step 17: out proj -> d_out ---
  k_gemm_mfma<<<512, 256, 0, stream>>>(wfo_h, wfo_l, anfh, anfl, out_b, (float*)d_out, 16, 8, 512);
}

// Round 15
// 545.593 us; speedup vs baseline: 1.1550x; 1.1550x over previous
//
#include <hip/hip_runtime.h>
#include <math.h>

// ---------------------------------------------------------------------------
// DAttention forward. R15: emb conv reverted to R13's proven tile (2 blocks/CU,
// 32-wide o-tile, double-buffered LDS — R14's 4/CU variant thrashed L2);
// dw9+cotail fusion kept. 16 dispatches.
// Dims: B=4, C=512, H=W=32, G=2, gc=256, BG=8, heads=8, hc=64, mh=8, mhd=32.
// ---------------------------------------------------------------------------

static constexpr int HW = 1024;

typedef __attribute__((ext_vector_type(8))) short bf16x8;
typedef __attribute__((ext_vector_type(4))) float f32x4;

union V16u { int4 i4; ushort u[8]; };

__device__ __forceinline__ float gelu_exact(float v) {
  return 0.5f * v * (1.0f + erff(v * 0.7071067811865475f));
}

__device__ __forceinline__ ushort bf16_rne(float v) {
  unsigned int b = __float_as_uint(v);
  return (ushort)((b + 0x7fffu + ((b >> 16) & 1u)) >> 16);
}

__device__ __forceinline__ void split2(float v, ushort& h, ushort& l) {
  h = bf16_rne(v);
  l = bf16_rne(v - __uint_as_float(((unsigned int)h) << 16));
}

// ---------------- weight frag body (shared); scale folded into weights
__device__ __forceinline__ void wfrag_body(const float* __restrict__ W, int K, int KC,
                                           ushort* __restrict__ dh, ushort* __restrict__ dl,
                                           int gtid, float scale) {
  int l = gtid & 63; int fr = gtid >> 6;
  int kc = fr % KC; int ot = fr / KC;
  int lr = l & 15, lu = l >> 4;
  const float* sp = W + (size_t)(ot * 16 + lr) * K + kc * 32 + lu * 8;
  V16u hi, lo;
#pragma unroll
  for (int j = 0; j < 8; ++j) split2(sp[j] * scale, hi.u[j], lo.u[j]);
  *(int4*)(dh + (size_t)gtid * 8) = hi.i4;
  *(int4*)(dl + (size_t)gtid * 8) = lo.i4;
}

// ---------------- MEGA-PREP. grid 6370.
__global__ void k_prep_all(
    const float* __restrict__ emb_w, const float* __restrict__ tgt,
    const float* __restrict__ refp,
    const float* q_w, const float* k_w, const float* v_w, const float* o_w,
    const float* mq_w, const float* mkv_w, const float* mp_w,
    const float* f1_w, const float* f2_w, const float* dw9_w,
    const float* q_b, const float* mq_b, const float* mkv_b,
    const float* k_b, const float* v_b,
    ushort* __restrict__ WtEH, ushort* __restrict__ WtEL,
    ushort* __restrict__ XtH, ushort* __restrict__ XtL,
    ushort* qh, ushort* ql, ushort* kvh, ushort* kvl,
    ushort* oh, ushort* ol, ushort* mqkvh, ushort* mqkvl,
    ushort* mph, ushort* mpl, ushort* f1h, ushort* f1l, ushort* f2h, ushort* f2l,
    float* wt9, float* biasmb, float* biaskv, float* biasq,
    ushort* tgtfh, ushort* tgtfl) {
  int bid = blockIdx.x, tid = threadIdx.x;
  if (bid < 2048) {                      // emb weights -> [9][512][1024] hi/lo
    int idx = bid * 256 + tid;
    int o = idx >> 10, ci = idx & 1023;
    const float* src = emb_w + (size_t)idx * 9;
#pragma unroll
    for (int t = 0; t < 9; ++t) {
      ushort h, l; split2(src[t], h, l);
      size_t oo = ((size_t)(t * 512 + o)) * 1024 + ci;
      WtEH[oo] = h; WtEL[oo] = l;
    }
  } else if (bid < 4360) {               // inputs -> [4][34][34][1024] hi/lo
    int idx = (bid - 2048) * 256 + tid;
    int xp = idx % 34; int r = idx / 34;
    int g8 = r & 127; r >>= 7;
    int yp = r % 34; int b = r / 34;
    int y = yp - 1, x = xp - 1;
    bool valid = (unsigned)y < 32u && (unsigned)x < 32u;
    V16u hi, lo;
    const float* in = (g8 < 64) ? (tgt + ((size_t)(b * 512 + g8 * 8)) * HW)
                                : (refp + ((size_t)(b * 512 + (g8 - 64) * 8)) * HW);
#pragma unroll
    for (int j = 0; j < 8; ++j) {
      float v = valid ? in[(size_t)j * HW + y * 32 + x] : 0.f;
      split2(v, hi.u[j], lo.u[j]);
    }
    size_t oo = (((size_t)(b * 34 + yp)) * 34 + xp) * 1024 + g8 * 8;
    *(int4*)(XtH + oo) = hi.i4;
    *(int4*)(XtL + oo) = lo.i4;
  }
  else if (bid < 4488) wfrag_body(q_w, 512, 16, qh, ql, (bid - 4360) * 256 + tid, 0.125f);
  else if (bid < 4616) wfrag_body(k_w, 512, 16, kvh, kvl, (bid - 4488) * 256 + tid, 1.f);
  else if (bid < 4744) wfrag_body(v_w, 512, 16, kvh + 262144, kvl + 262144,
                                  (bid - 4616) * 256 + tid, 1.f);
  else if (bid < 4872) wfrag_body(o_w, 512, 16, oh, ol, (bid - 4744) * 256 + tid, 1.f);
  else if (bid < 4904) wfrag_body(mq_w, 256, 8, mqkvh, mqkvl, (bid - 4872) * 256 + tid,
                                  0.17677669529663689f);
  else if (bid < 4968) wfrag_body(mkv_w, 256, 8, mqkvh + 65536, mqkvl + 65536,
                                  (bid - 4904) * 256 + tid, 1.f);
  else if (bid < 5000) wfrag_body(mp_w, 256, 8, mph, mpl, (bid - 4968) * 256 + tid, 1.f);
  else if (bid < 5128) wfrag_body(f1_w, 256, 8, f1h, f1l, (bid - 5000) * 256 + tid, 1.f);
  else if (bid < 5256) wfrag_body(f2_w, 1024, 32, f2h, f2l, (bid - 5128) * 256 + tid, 1.f);
  else if (bid < 5337) {                 // dw9 weight transpose [81][256]
    int idx = (bid - 5256) * 256 + tid;
    int t = idx >> 8, c = idx & 255;
    wt9[idx] = dw9_w[c * 81 + t];
  } else if (bid < 5346) {               // biases
    int idx = (bid - 5337) * 256 + tid;
    if (idx < 768)
      biasmb[idx] = idx < 256 ? mq_b[idx] * 0.17677669529663689f : mkv_b[idx - 256];
    else if (idx < 1792) {
      int j = idx - 768;
      biaskv[j] = j < 512 ? k_b[j] : v_b[j - 512];
    } else if (idx < 2304) {
      biasq[idx - 1792] = q_b[idx - 1792] * 0.125f;
    }
  } else {                               // tgt cm -> B-frags (1024 blocks)
    int gtid = (bid - 5346) * 256 + tid;
    int l = gtid & 63; int fr = gtid >> 6;
    int kc = fr % 16; int r2 = fr / 16; int nt = r2 & 63; int b = r2 >> 6;
    int lr = l & 15, lu = l >> 4;
    const float* sp = tgt + ((size_t)(b * 512) + kc * 32 + lu * 8) * 1024 + nt * 16 + lr;
    V16u hi, lo;
#pragma unroll
    for (int j = 0; j < 8; ++j) split2(sp[(size_t)j * 1024], hi.u[j], lo.u[j]);
    *(int4*)(tgtfh + (size_t)gtid * 8) = hi.i4;
    *(int4*)(tgtfl + (size_t)gtid * 8) = lo.i4;
  }
}

// ---------------- emb conv via MFMA (R13 proven tile): split-bf16, 4-way
// K-split, 4 rows/wave, 32-wide o-tile, double-buffered LDS, 2 blocks/CU.
__global__ __launch_bounds__(256, 2)
void k_emb_mfma(const ushort* __restrict__ Xt_hi, const ushort* __restrict__ Xt_lo,
                const ushort* __restrict__ Wt_hi, const ushort* __restrict__ Wt_lo,
                float* __restrict__ part) {
  int wgid = (blockIdx.x & 7) * 64 + (blockIdx.x >> 3);
  int yt = wgid & 7;  wgid >>= 3;
  int b  = wgid & 3;  wgid >>= 2;
  int mt = wgid & 3;  wgid >>= 2;
  int ks = wgid;
  int tid = threadIdx.x;
  int w = tid >> 6, l = tid & 63;
  int lr = l & 15, lu = l >> 4;
  int y0 = yt * 4;
  int obase = mt * 128 + w * 32;

  __shared__ int4 LsH[2][816];
  __shared__ int4 LsL[2][816];

  int4 gh[4], gl[4];
  int kc0 = ks * 8;

  auto loadstage = [&](int kcg) {
#pragma unroll
    for (int i = 0; i < 4; ++i) {
      int s = tid + 256 * i;
      if (s < 816) {
        int px = s >> 2;
        int u = (s & 3) ^ ((px >> 1) & 3);
        size_t off = ((size_t)(b * 34 + y0) * 34 + px) * 1024 + kcg * 32 + u * 8;
        gh[i] = *(const int4*)(Xt_hi + off);
        gl[i] = *(const int4*)(Xt_lo + off);
      }
    }
  };
  auto writestage = [&](int buf) {
#pragma unroll
    for (int i = 0; i < 4; ++i) {
      int s = tid + 256 * i;
      if (s < 816) { LsH[buf][s] = gh[i]; LsL[buf][s] = gl[i]; }
    }
  };

  f32x4 zero = {0.f, 0.f, 0.f, 0.f};
  f32x4 acc[2][8];
#pragma unroll
  for (int a = 0; a < 2; ++a)
#pragma unroll
    for (int n = 0; n < 8; ++n) acc[a][n] = zero;

  loadstage(kc0);
  writestage(0);

  for (int kc = 0; kc < 8; ++kc) {
    int buf = kc & 1;
    __syncthreads();
    if (kc < 7) loadstage(kc0 + kc + 1);
    int kcg = kc0 + kc;
    const bf16x8* BH = (const bf16x8*)&LsH[buf][0];
    const bf16x8* BL = (const bf16x8*)&LsL[buf][0];
#pragma unroll
    for (int kx = 0; kx < 3; ++kx) {
      bf16x8 bh[12], bl[12];
#pragma unroll
      for (int f = 0; f < 12; ++f) {
        int px = (f >> 1) * 34 + (f & 1) * 16 + kx + lr;
        int idx = px * 4 + (lu ^ ((px >> 1) & 3));
        bh[f] = BH[idx]; bl[f] = BL[idx];
      }
#pragma unroll
      for (int ky = 0; ky < 3; ++ky) {
        int tap = ky * 3 + kx;
        size_t wo = (((size_t)(tap * 512 + obase + lr)) * 1024) + kcg * 32 + lu * 8;
        bf16x8 ah0 = *(const bf16x8*)(Wt_hi + wo);
        bf16x8 al0 = *(const bf16x8*)(Wt_lo + wo);
        bf16x8 ah1 = *(const bf16x8*)(Wt_hi + wo + 16 * 1024);
        bf16x8 al1 = *(const bf16x8*)(Wt_lo + wo + 16 * 1024);
#pragma unroll
        for (int yr = 0; yr < 4; ++yr)
#pragma unroll
          for (int h = 0; h < 2; ++h) {
            int f = (yr + ky) * 2 + h;
            int nf = yr * 2 + h;
            acc[0][nf] = __builtin_amdgcn_mfma_f32_16x16x32_bf16(ah0, bh[f], acc[0][nf], 0, 0, 0);
            acc[0][nf] = __builtin_amdgcn_mfma_f32_16x16x32_bf16(ah0, bl[f], acc[0][nf], 0, 0, 0);
            acc[0][nf] = __builtin_amdgcn_mfma_f32_16x16x32_bf16(al0, bh[f], acc[0][nf], 0, 0, 0);
            acc[1][nf] = __builtin_amdgcn_mfma_f32_16x16x32_bf16(ah1, bh[f], acc[1][nf], 0, 0, 0);
            acc[1][nf] = __builtin_amdgcn_mfma_f32_16x16x32_bf16(ah1, bl[f], acc[1][nf], 0, 0, 0);
            acc[1][nf] = __builtin_amdgcn_mfma_f32_16x16x32_bf16(al1, bh[f], acc[1][nf], 0, 0, 0);
          }
      }
    }
    if (kc < 7) writestage(buf ^ 1);
  }

  float* pb = part + (size_t)ks * 2097152;
#pragma unroll
  for (int a = 0; a < 2; ++a)
#pragma unroll
    for (int yr = 0; yr < 4; ++yr)
#pragma unroll
      for (int h = 0; h < 2; ++h) {
        f32x4 c = acc[a][yr * 2 + h];
        size_t base = ((size_t)(b * 512 + obase + a * 16 + lu * 4)) * 1024
                      + (y0 + yr) * 32 + h * 16 + lr;
#pragma unroll
        for (int r = 0; r < 4; ++r) pb[base + (size_t)r * 1024] = c[r];
      }
}

// ---------------- emb merge: sum 4 parts + bias, write feat_nc (transposing)
__global__ void k_embmerge_nc(const float* __restrict__ part, const float* __restrict__ bias,
                              float* __restrict__ featnc) {
  __shared__ float T[64][65];
  int bid = blockIdx.x;
  int n0 = (bid & 15) << 6; bid >>= 4;
  int c0 = (bid & 3) << 6; int bg = bid >> 2;
  int cl = threadIdx.x & 63, rw = threadIdx.x >> 6;
#pragma unroll
  for (int i = 0; i < 16; ++i) {
    int crow = i * 4 + rw;
    size_t idx = ((size_t)(bg * 256 + c0 + crow)) * 1024 + n0 + cl;
    float v = part[idx] + part[2097152 + idx] + part[4194304 + idx] + part[6291456 + idx];
    T[crow][cl] = v + bias[(bg & 1) * 256 + c0 + crow];
  }
  __syncthreads();
#pragma unroll
  for (int i = 0; i < 16; ++i) {
    int nrow = i * 4 + rw;
    featnc[((size_t)(bg * 1024 + n0 + nrow)) * 256 + c0 + cl] = T[cl][nrow];
  }
}

// ============ generic MFMA GEMM (cm fp32 output) ============
__global__ __launch_bounds__(256)
void k_gemm_mfma(const ushort* __restrict__ Ah, const ushort* __restrict__ Al,
                 const ushort* __restrict__ Bh, const ushort* __restrict__ Bl,
                 const float* __restrict__ bias, float* __restrict__ Y,
                 int KC, int MT, int Mtot) {
  int bid = blockIdx.x;
  int ntb = bid & 15; bid >>= 4;
  int mt = bid % MT; int b = bid / MT;
  int tid = threadIdx.x, w = tid >> 6, l = tid & 63, lr = l & 15, lu = l >> 4;
  int wo = w >> 1, wn = w & 1;
  int ot0 = mt * 4 + wo * 2;
  int nf0 = ntb * 4 + wn * 2;
  const bf16x8* pAh = (const bf16x8*)Ah;
  const bf16x8* pAl = (const bf16x8*)Al;
  const bf16x8* pBh = (const bf16x8*)Bh;
  const bf16x8* pBl = (const bf16x8*)Bl;
  f32x4 zero = {0.f, 0.f, 0.f, 0.f};
  f32x4 acc[2][2];
#pragma unroll
  for (int a = 0; a < 2; ++a)
#pragma unroll
    for (int n = 0; n < 2; ++n) acc[a][n] = zero;
  for (int kc = 0; kc < KC; ++kc) {
    bf16x8 a_h[2], a_l[2];
#pragma unroll
    for (int a = 0; a < 2; ++a) {
      size_t idx = ((size_t)(ot0 + a) * KC + kc) * 64 + l;
      a_h[a] = pAh[idx]; a_l[a] = pAl[idx];
    }
#pragma unroll
    for (int n = 0; n < 2; ++n) {
      size_t idx = (((size_t)(b * 64 + nf0 + n)) * KC + kc) * 64 + l;
      bf16x8 b_h = pBh[idx], b_l = pBl[idx];
#pragma unroll
      for (int a = 0; a < 2; ++a) {
        acc[a][n] = __builtin_amdgcn_mfma_f32_16x16x32_bf16(a_h[a], b_h, acc[a][n], 0, 0, 0);
        acc[a][n] = __builtin_amdgcn_mfma_f32_16x16x32_bf16(a_h[a], b_l, acc[a][n], 0, 0, 0);
        acc[a][n] = __builtin_amdgcn_mfma_f32_16x16x32_bf16(a_l[a], b_h, acc[a][n], 0, 0, 0);
      }
    }
  }
#pragma unroll
  for (int a = 0; a < 2; ++a) {
    int o = (ot0 + a) * 16 + lu * 4;
#pragma unroll
    for (int n = 0; n < 2; ++n) {
      int col = (nf0 + n) * 16 + lr;
#pragma unroll
      for (int r = 0; r < 4; ++r)
        Y[((size_t)(b * Mtot + o + r)) * 1024 + col] = acc[a][n][r] + bias[o + r];
    }
  }
}

// ============ GEMM with token-major residual epilogue (Mtot=256) ============
__global__ __launch_bounds__(256)
void k_gemm_resadd(const ushort* __restrict__ Ah, const ushort* __restrict__ Al,
                   const ushort* __restrict__ Bh, const ushort* __restrict__ Bl,
                   const float* __restrict__ bias, const float* __restrict__ res,
                   float* __restrict__ dst, int KC, int MT, int addmode) {
  int bid = blockIdx.x;
  int ntb = bid & 15; bid >>= 4;
  int mt = bid % MT; int b = bid / MT;
  int tid = threadIdx.x, w = tid >> 6, l = tid & 63, lr = l & 15, lu = l >> 4;
  int wo = w >> 1, wn = w & 1;
  int ot0 = mt * 4 + wo * 2;
  int nf0 = ntb * 4 + wn * 2;
  const bf16x8* pAh = (const bf16x8*)Ah;
  const bf16x8* pAl = (const bf16x8*)Al;
  const bf16x8* pBh = (const bf16x8*)Bh;
  const bf16x8* pBl = (const bf16x8*)Bl;
  f32x4 zero = {0.f, 0.f, 0.f, 0.f};
  f32x4 acc[2][2];
#pragma unroll
  for (int a = 0; a < 2; ++a)
#pragma unroll
    for (int n = 0; n < 2; ++n) acc[a][n] = zero;
  for (int kc = 0; kc < KC; ++kc) {
    bf16x8 a_h[2], a_l[2];
#pragma unroll
    for (int a = 0; a < 2; ++a) {
      size_t idx = ((size_t)(ot0 + a) * KC + kc) * 64 + l;
      a_h[a] = pAh[idx]; a_l[a] = pAl[idx];
    }
#pragma unroll
    for (int n = 0; n < 2; ++n) {
      size_t idx = (((size_t)(b * 64 + nf0 + n)) * KC + kc) * 64 + l;
      bf16x8 b_h = pBh[idx], b_l = pBl[idx];
#pragma unroll
      for (int a = 0; a < 2; ++a) {
        acc[a][n] = __builtin_amdgcn_mfma_f32_16x16x32_bf16(a_h[a], b_h, acc[a][n], 0, 0, 0);
        acc[a][n] = __builtin_amdgcn_mfma_f32_16x16x32_bf16(a_h[a], b_l, acc[a][n], 0, 0, 0);
        acc[a][n] = __builtin_amdgcn_mfma_f32_16x16x32_bf16(a_l[a], b_h, acc[a][n], 0, 0, 0);
      }
    }
  }
#pragma unroll
  for (int a = 0; a < 2; ++a) {
    int o = (ot0 + a) * 16 + lu * 4;
#pragma unroll
    for (int n = 0; n < 2; ++n) {
      int col = (nf0 + n) * 16 + lr;
      size_t addr = ((size_t)((b << 10) + col)) * 256 + o;
      float4 v;
      v.x = acc[a][n][0] + bias[o + 0];
      v.y = acc[a][n][1] + bias[o + 1];
      v.z = acc[a][n][2] + bias[o + 2];
      v.w = acc[a][n][3] + bias[o + 3];
      float4 r4 = addmode ? *(const float4*)(dst + addr) : *(const float4*)(res + addr);
      v.x += r4.x; v.y += r4.y; v.z += r4.z; v.w += r4.w;
      *(float4*)(dst + addr) = v;
    }
  }
}

// ============ GEMM with mb-attention frag epilogue (d=32 heads) ============
__global__ __launch_bounds__(256)
void k_gemm_frag_mb(const ushort* __restrict__ Ah, const ushort* __restrict__ Al,
                    const ushort* __restrict__ Bh, const ushort* __restrict__ Bl,
                    const float* __restrict__ bias,
                    ushort* __restrict__ mQh, ushort* __restrict__ mQl,
                    ushort* __restrict__ mKh, ushort* __restrict__ mKl,
                    ushort* __restrict__ mVh, ushort* __restrict__ mVl) {
  int bid = blockIdx.x;
  int ntb = bid & 15; bid >>= 4;
  int mt = bid % 12; int b = bid / 12;
  int tid = threadIdx.x, w = tid >> 6, l = tid & 63, lr = l & 15, lu = l >> 4;
  int wo = w >> 1, wn = w & 1;
  int ot0 = mt * 4 + wo * 2;
  int nf0 = ntb * 4 + wn * 2;
  const bf16x8* pAh = (const bf16x8*)Ah;
  const bf16x8* pAl = (const bf16x8*)Al;
  const bf16x8* pBh = (const bf16x8*)Bh;
  const bf16x8* pBl = (const bf16x8*)Bl;
  f32x4 zero = {0.f, 0.f, 0.f, 0.f};
  f32x4 acc[2][2];
#pragma unroll
  for (int a = 0; a < 2; ++a)
#pragma unroll
    for (int n = 0; n < 2; ++n) acc[a][n] = zero;
  for (int kc = 0; kc < 8; ++kc) {
    bf16x8 a_h[2], a_l[2];
#pragma unroll
    for (int a = 0; a < 2; ++a) {
      size_t idx = ((size_t)(ot0 + a) * 8 + kc) * 64 + l;
      a_h[a] = pAh[idx]; a_l[a] = pAl[idx];
    }
#pragma unroll
    for (int n = 0; n < 2; ++n) {
      size_t idx = (((size_t)(b * 64 + nf0 + n)) * 8 + kc) * 64 + l;
      bf16x8 b_h = pBh[idx], b_l = pBl[idx];
#pragma unroll
      for (int a = 0; a < 2; ++a) {
        acc[a][n] = __builtin_amdgcn_mfma_f32_16x16x32_bf16(a_h[a], b_h, acc[a][n], 0, 0, 0);
        acc[a][n] = __builtin_amdgcn_mfma_f32_16x16x32_bf16(a_h[a], b_l, acc[a][n], 0, 0, 0);
        acc[a][n] = __builtin_amdgcn_mfma_f32_16x16x32_bf16(a_l[a], b_h, acc[a][n], 0, 0, 0);
      }
    }
  }
#pragma unroll
  for (int a = 0; a < 2; ++a) {
    int o0 = (ot0 + a) * 16 + lu * 4;
#pragma unroll
    for (int n = 0; n < 2; ++n) {
      int col = (nf0 + n) * 16 + lr;
      ushort4 h4, l4;
      split2(acc[a][n][0] + bias[o0 + 0], h4.x, l4.x);
      split2(acc[a][n][1] + bias[o0 + 1], h4.y, l4.y);
      split2(acc[a][n][2] + bias[o0 + 2], h4.z, l4.z);
      split2(acc[a][n][3] + bias[o0 + 3], h4.w, l4.w);
      if (o0 < 512) {
        int oo = o0 & 255;
        int hh = oo >> 5, d = oo & 31;
        ushort* dh = o0 < 256 ? mQh : mKh;
        ushort* dl = o0 < 256 ? mQl : mKl;
        size_t base = ((((size_t)(b * 8 + hh) * 64 + (col >> 4)) * 64)
                       + ((d >> 3) << 4) + (col & 15)) * 8 + (d & 7);
        *(ushort4*)(dh + base) = h4;
        *(ushort4*)(dl + base) = l4;
      } else {
        int oo = o0 - 512;
        int hh = oo >> 5, d = oo & 31;
        int et = d >> 4;
        size_t eb = ((((size_t)((b * 8 + hh) * 2 + et)) * 32 + (col >> 5)) * 64
                     + ((col >> 3) & 3) * 16 + (d & 15)) * 8 + (col & 7);
        mVh[eb] = h4.x; mVh[eb + 8] = h4.y; mVh[eb + 16] = h4.z; mVh[eb + 24] = h4.w;
        mVl[eb] = l4.x; mVl[eb + 8] = l4.y; mVl[eb + 16] = l4.z; mVl[eb + 24] = l4.w;
      }
    }
  }
}

// ============ GEMM with main-attention frag epilogue (d=64 heads) ============
__global__ __launch_bounds__(256)
void k_gemm_frag_main(const ushort* __restrict__ Ah, const ushort* __restrict__ Al,
                      const ushort* __restrict__ Bh, const ushort* __restrict__ Bl,
                      const float* __restrict__ bias,
                      ushort* __restrict__ fh, ushort* __restrict__ fl,
                      ushort* __restrict__ vfh, ushort* __restrict__ vfl,
                      int vbase, int KC, int MT) {
  int bid = blockIdx.x;
  int ntb = bid & 15; bid >>= 4;
  int mt = bid % MT; int b = bid / MT;
  int tid = threadIdx.x, w = tid >> 6, l = tid & 63, lr = l & 15, lu = l >> 4;
  int wo = w >> 1, wn = w & 1;
  int ot0 = mt * 4 + wo * 2;
  int nf0 = ntb * 4 + wn * 2;
  const bf16x8* pAh = (const bf16x8*)Ah;
  const bf16x8* pAl = (const bf16x8*)Al;
  const bf16x8* pBh = (const bf16x8*)Bh;
  const bf16x8* pBl = (const bf16x8*)Bl;
  f32x4 zero = {0.f, 0.f, 0.f, 0.f};
  f32x4 acc[2][2];
#pragma unroll
  for (int a = 0; a < 2; ++a)
#pragma unroll
    for (int n = 0; n < 2; ++n) acc[a][n] = zero;
  for (int kc = 0; kc < KC; ++kc) {
    bf16x8 a_h[2], a_l[2];
#pragma unroll
    for (int a = 0; a < 2; ++a) {
      size_t idx = ((size_t)(ot0 + a) * KC + kc) * 64 + l;
      a_h[a] = pAh[idx]; a_l[a] = pAl[idx];
    }
#pragma unroll
    for (int n = 0; n < 2; ++n) {
      size_t idx = (((size_t)(b * 64 + nf0 + n)) * KC + kc) * 64 + l;
      bf16x8 b_h = pBh[idx], b_l = pBl[idx];
#pragma unroll
      for (int a = 0; a < 2; ++a) {
        acc[a][n] = __builtin_amdgcn_mfma_f32_16x16x32_bf16(a_h[a], b_h, acc[a][n], 0, 0, 0);
        acc[a][n] = __builtin_amdgcn_mfma_f32_16x16x32_bf16(a_h[a], b_l, acc[a][n], 0, 0, 0);
        acc[a][n] = __builtin_amdgcn_mfma_f32_16x16x32_bf16(a_l[a], b_h, acc[a][n], 0, 0, 0);
      }
    }
  }
#pragma unroll
  for (int a = 0; a < 2; ++a) {
    int o0 = (ot0 + a) * 16 + lu * 4;
#pragma unroll
    for (int n = 0; n < 2; ++n) {
      int col = (nf0 + n) * 16 + lr;
      ushort4 h4, l4;
      split2(acc[a][n][0] + bias[o0 + 0], h4.x, l4.x);
      split2(acc[a][n][1] + bias[o0 + 1], h4.y, l4.y);
      split2(acc[a][n][2] + bias[o0 + 2], h4.z, l4.z);
      split2(acc[a][n][3] + bias[o0 + 3], h4.w, l4.w);
      if (o0 < vbase) {
        int h = o0 >> 6, d = o0 & 63;
        int dc = d >> 5;
        size_t base = (((((size_t)(b * 8 + h) * 64 + (col >> 4)) * 2 + dc) * 64)
                       + (((d & 31) >> 3) << 4) + (col & 15)) * 8 + (d & 7);
        *(ushort4*)(fh + base) = h4;
        *(ushort4*)(fl + base) = l4;
      } else {
        int oo = o0 - vbase;
        int h = oo >> 6, d = oo & 63;
        int et = d >> 4;
        size_t eb = ((((size_t)((b * 8 + h) * 4 + et)) * 32 + (col >> 5)) * 64
                     + ((col >> 3) & 3) * 16 + (d & 15)) * 8 + (col & 7);
        vfh[eb] = h4.x; vfh[eb + 8] = h4.y; vfh[eb + 16] = h4.z; vfh[eb + 24] = h4.w;
        vfl[eb] = l4.x; vfl[eb + 8] = l4.y; vfl[eb + 16] = l4.z; vfl[eb + 24] = l4.w;
      }
    }
  }
}

// ---------------- FUSED ln1 (->xbuf) + n1 (->B-frags), wave per token
__global__ void k_ln1n1(const float* __restrict__ featnc,
                        const float* __restrict__ g1, const float* __restrict__ b1,
                        const float* __restrict__ gn, const float* __restrict__ bn,
                        float* __restrict__ xbuf,
                        ushort* __restrict__ dh, ushort* __restrict__ dl) {
  int token = (blockIdx.x * 256 + threadIdx.x) >> 6;
  int lane = threadIdx.x & 63;
  float4 v4 = *reinterpret_cast<const float4*>(featnc + (size_t)token * 256 + lane * 4);
  float s  = v4.x + v4.y + v4.z + v4.w;
  float s2 = v4.x * v4.x + v4.y * v4.y + v4.z * v4.z + v4.w * v4.w;
#pragma unroll
  for (int off = 32; off; off >>= 1) { s += __shfl_xor(s, off); s2 += __shfl_xor(s2, off); }
  float mean = s * (1.f / 256.f);
  float rstd = rsqrtf(s2 * (1.f / 256.f) - mean * mean + 1e-5f);
  float4 g4 = *reinterpret_cast<const float4*>(g1 + lane * 4);
  float4 b4 = *reinterpret_cast<const float4*>(b1 + lane * 4);
  float4 x;
  x.x = (v4.x - mean) * rstd * g4.x + b4.x;
  x.y = (v4.y - mean) * rstd * g4.y + b4.y;
  x.z = (v4.z - mean) * rstd * g4.z + b4.z;
  x.w = (v4.w - mean) * rstd * g4.w + b4.w;
  *reinterpret_cast<float4*>(xbuf + (size_t)token * 256 + lane * 4) = x;
  float t  = x.x + x.y + x.z + x.w;
  float t2 = x.x * x.x + x.y * x.y + x.z * x.z + x.w * x.w;
#pragma unroll
  for (int off = 32; off; off >>= 1) { t += __shfl_xor(t, off); t2 += __shfl_xor(t2, off); }
  float mean2 = t * (1.f / 256.f);
  float rstd2 = rsqrtf(t2 * (1.f / 256.f) - mean2 * mean2 + 1e-6f);
  float4 gg = *reinterpret_cast<const float4*>(gn + lane * 4);
  float4 bb = *reinterpret_cast<const float4*>(bn + lane * 4);
  ushort4 h4, l4;
  split2((x.x - mean2) * rstd2 * gg.x + bb.x, h4.x, l4.x);
  split2((x.y - mean2) * rstd2 * gg.y + bb.y, h4.y, l4.y);
  split2((x.z - mean2) * rstd2 * gg.z + bb.z, h4.z, l4.z);
  split2((x.w - mean2) * rstd2 * gg.w + bb.w, h4.w, l4.w);
  int bg = token >> 10, nt = (token >> 4) & 63, lr = token & 15;
  int kc = lane >> 3, lu_f = (lane >> 1) & 3, j0 = (lane & 1) * 4;
  size_t base = ((((size_t)(bg * 64 + nt)) * 8 + kc) * 64 + lu_f * 16 + lr) * 8 + j0;
  *(ushort4*)(dh + base) = h4;
  *(ushort4*)(dl + base) = l4;
}

// ---------------- token-major LN -> B-frags (KC=8), standalone (n2)
__global__ void k_ln_frag(const float* __restrict__ xin, const float* __restrict__ g_,
                          const float* __restrict__ b_, ushort* __restrict__ dh,
                          ushort* __restrict__ dl, float eps) {
  int token = (blockIdx.x * 256 + threadIdx.x) >> 6;
  int lane = threadIdx.x & 63;
  float4 v4 = *reinterpret_cast<const float4*>(xin + (size_t)token * 256 + lane * 4);
  float s  = v4.x + v4.y + v4.z + v4.w;
  float s2 = v4.x * v4.x + v4.y * v4.y + v4.z * v4.z + v4.w * v4.w;
#pragma unroll
  for (int off = 32; off; off >>= 1) { s += __shfl_xor(s, off); s2 += __shfl_xor(s2, off); }
  float mean = s * (1.f / 256.f);
  float rstd = rsqrtf(s2 * (1.f / 256.f) - mean * mean + eps);
  float4 g4 = *reinterpret_cast<const float4*>(g_ + lane * 4);
  float4 b4 = *reinterpret_cast<const float4*>(b_ + lane * 4);
  ushort4 h4, l4;
  split2((v4.x - mean) * rstd * g4.x + b4.x, h4.x, l4.x);
  split2((v4.y - mean) * rstd * g4.y + b4.y, h4.y, l4.y);
  split2((v4.z - mean) * rstd * g4.z + b4.z, h4.z, l4.z);
  split2((v4.w - mean) * rstd * g4.w + b4.w, h4.w, l4.w);
  int bg = token >> 10, nt = (token >> 4) & 63, lr = token & 15;
  int kc = lane >> 3, lu_f = (lane >> 1) & 3, j0 = (lane & 1) * 4;
  size_t base = ((((size_t)(bg * 64 + nt)) * 8 + kc) * 64 + lu_f * 16 + lr) * 8 + j0;
  *(ushort4*)(dh + base) = h4;
  *(ushort4*)(dl + base) = l4;
}

// ============ MitBlock attention (MFMA, d=32), epilogue -> B-frags ============
__global__ __launch_bounds__(256)
void k_mbattn_mfma(const ushort* __restrict__ Qh, const ushort* __restrict__ Ql,
                   const ushort* __restrict__ Kh, const ushort* __restrict__ Kl,
                   const ushort* __restrict__ Vh, const ushort* __restrict__ Vl,
                   ushort* __restrict__ ofh, ushort* __restrict__ ofl) {
  int qb = blockIdx.x & 15, bgh = blockIdx.x >> 4;
  int tid = threadIdx.x, w = tid >> 6, l = tid & 63, lr = l & 15, lu = l >> 4;
  int qt = qb * 4 + w;
  bf16x8 qh = ((const bf16x8*)Qh)[(size_t)(bgh * 64 + qt) * 64 + l];
  bf16x8 ql = ((const bf16x8*)Ql)[(size_t)(bgh * 64 + qt) * 64 + l];
  __shared__ ushort Ph[4][16][72];
  __shared__ ushort Pl[4][16][72];
  f32x4 zero = {0.f, 0.f, 0.f, 0.f};
  f32x4 oacc[2] = {zero, zero};
  float den = 0.f;
  for (int kb = 0; kb < 16; ++kb) {
#pragma unroll
    for (int kt4 = 0; kt4 < 4; ++kt4) {
      int kt = kb * 4 + kt4;
      bf16x8 kh = ((const bf16x8*)Kh)[(size_t)(bgh * 64 + kt) * 64 + l];
      bf16x8 kl = ((const bf16x8*)Kl)[(size_t)(bgh * 64 + kt) * 64 + l];
      f32x4 s = zero;
      s = __builtin_amdgcn_mfma_f32_16x16x32_bf16(kh, qh, s, 0, 0, 0);
      s = __builtin_amdgcn_mfma_f32_16x16x32_bf16(kh, ql, s, 0, 0, 0);
      s = __builtin_amdgcn_mfma_f32_16x16x32_bf16(kl, qh, s, 0, 0, 0);
      uint2 uh, ul;
      {
        float p0 = __expf(s[0]), p1 = __expf(s[1]), p2 = __expf(s[2]), p3 = __expf(s[3]);
        den += (p0 + p1) + (p2 + p3);
        ushort h0, l0, h1, l1, h2, l2, h3, l3;
        split2(p0, h0, l0); split2(p1, h1, l1); split2(p2, h2, l2); split2(p3, h3, l3);
        uh.x = (unsigned)h0 | ((unsigned)h1 << 16); uh.y = (unsigned)h2 | ((unsigned)h3 << 16);
        ul.x = (unsigned)l0 | ((unsigned)l1 << 16); ul.y = (unsigned)l2 | ((unsigned)l3 << 16);
      }
      *(uint2*)&Ph[w][lr][kt4 * 16 + lu * 4] = uh;
      *(uint2*)&Pl[w][lr][kt4 * 16 + lu * 4] = ul;
    }
#pragma unroll
    for (int kc2 = 0; kc2 < 2; ++kc2) {
      int kc = kb * 2 + kc2;
      bf16x8 bph = *(const bf16x8*)&Ph[w][lr][kc2 * 32 + lu * 8];
      bf16x8 bpl = *(const bf16x8*)&Pl[w][lr][kc2 * 32 + lu * 8];
#pragma unroll
      for (int et = 0; et < 2; ++et) {
        bf16x8 vh = ((const bf16x8*)Vh)[(size_t)((bgh * 2 + et) * 32 + kc) * 64 + l];
        bf16x8 vl = ((const bf16x8*)Vl)[(size_t)((bgh * 2 + et) * 32 + kc) * 64 + l];
        oacc[et] = __builtin_amdgcn_mfma_f32_16x16x32_bf16(vh, bph, oacc[et], 0, 0, 0);
        oacc[et] = __builtin_amdgcn_mfma_f32_16x16x32_bf16(vh, bpl, oacc[et], 0, 0, 0);
        oacc[et] = __builtin_amdgcn_mfma_f32_16x16x32_bf16(vl, bph, oacc[et], 0, 0, 0);
      }
    }
  }
  den += __shfl_xor(den, 16);
  den += __shfl_xor(den, 32);
  float inv = 1.f / den;
  int bg = bgh >> 3, hh = bgh & 7;
#pragma unroll
  for (int et = 0; et < 2; ++et) {
    ushort4 h4, l4;
    split2(oacc[et][0] * inv, h4.x, l4.x); split2(oacc[et][1] * inv, h4.y, l4.y);
    split2(oacc[et][2] * inv, h4.z, l4.z); split2(oacc[et][3] * inv, h4.w, l4.w);
    int lu_f = et * 2 + (lu >> 1), j0 = (lu & 1) * 4;
    size_t base = ((((size_t)(bg * 64 + qt)) * 8 + hh) * 64 + lu_f * 16 + lr) * 8 + j0;
    *(ushort4*)(ofh + base) = h4;
    *(ushort4*)(ofl + base) = l4;
  }
}

// ============ main attention (MFMA, d=64), epilogue -> B-frags (KC=16) ========
__global__ __launch_bounds__(256)
void k_mainattn_mfma(const ushort* __restrict__ Qh, const ushort* __restrict__ Ql,
                     const ushort* __restrict__ Kh, const ushort* __restrict__ Kl,
                     const ushort* __restrict__ Vh, const ushort* __restrict__ Vl,
                     ushort* __restrict__ anfh, ushort* __restrict__ anfl) {
  int qb = blockIdx.x & 15, bh = blockIdx.x >> 4;
  int tid = threadIdx.x, w = tid >> 6, l = tid & 63, lr = l & 15, lu = l >> 4;
  int qt = qb * 4 + w;
  bf16x8 qh[2], ql[2];
#pragma unroll
  for (int dc = 0; dc < 2; ++dc) {
    qh[dc] = ((const bf16x8*)Qh)[(size_t)((bh * 64 + qt) * 2 + dc) * 64 + l];
    ql[dc] = ((const bf16x8*)Ql)[(size_t)((bh * 64 + qt) * 2 + dc) * 64 + l];
  }
  __shared__ ushort Ph[4][16][72];
  __shared__ ushort Pl[4][16][72];
  f32x4 zero = {0.f, 0.f, 0.f, 0.f};
  f32x4 oacc[4] = {zero, zero, zero, zero};
  float den = 0.f;
  for (int kb = 0; kb < 16; ++kb) {
#pragma unroll
    for (int kt4 = 0; kt4 < 4; ++kt4) {
      int kt = kb * 4 + kt4;
      f32x4 s = zero;
#pragma unroll
      for (int dc = 0; dc < 2; ++dc) {
        bf16x8 kh = ((const bf16x8*)Kh)[(size_t)((bh * 64 + kt) * 2 + dc) * 64 + l];
        bf16x8 kl = ((const bf16x8*)Kl)[(size_t)((bh * 64 + kt) * 2 + dc) * 64 + l];
        s = __builtin_amdgcn_mfma_f32_16x16x32_bf16(kh, qh[dc], s, 0, 0, 0);
        s = __builtin_amdgcn_mfma_f32_16x16x32_bf16(kh, ql[dc], s, 0, 0, 0);
        s = __builtin_amdgcn_mfma_f32_16x16x32_bf16(kl, qh[dc], s, 0, 0, 0);
      }
      uint2 uh, ul;
      {
        float p0 = __expf(s[0]), p1 = __expf(s[1]), p2 = __expf(s[2]), p3 = __expf(s[3]);
        den += (p0 + p1) + (p2 + p3);
        ushort h0, l0, h1, l1, h2, l2, h3, l3;
        split2(p0, h0, l0); split2(p1, h1, l1); split2(p2, h2, l2); split2(p3, h3, l3);
        uh.x = (unsigned)h0 | ((unsigned)h1 << 16); uh.y = (unsigned)h2 | ((unsigned)h3 << 16);
        ul.x = (unsigned)l0 | ((unsigned)l1 << 16); ul.y = (unsigned)l2 | ((unsigned)l3 << 16);
      }
      *(uint2*)&Ph[w][lr][kt4 * 16 + lu * 4] = uh;
      *(uint2*)&Pl[w][lr][kt4 * 16 + lu * 4] = ul;
    }
#pragma unroll
    for (int kc2 = 0; kc2 < 2; ++kc2) {
      int kc = kb * 2 + kc2;
      bf16x8 bph = *(const bf16x8*)&Ph[w][lr][kc2 * 32 + lu * 8];
      bf16x8 bpl = *(const bf16x8*)&Pl[w][lr][kc2 * 32 + lu * 8];
#pragma unroll
      for (int et = 0; et < 4; ++et) {
        bf16x8 vh = ((const bf16x8*)Vh)[(size_t)((bh * 4 + et) * 32 + kc) * 64 + l];
        bf16x8 vl = ((const bf16x8*)Vl)[(size_t)((bh * 4 + et) * 32 + kc) * 64 + l];
        oacc[et] = __builtin_amdgcn_mfma_f32_16x16x32_bf16(vh, bph, oacc[et], 0, 0, 0);
        oacc[et] = __builtin_amdgcn_mfma_f32_16x16x32_bf16(vh, bpl, oacc[et], 0, 0, 0);
        oacc[et] = __builtin_amdgcn_mfma_f32_16x16x32_bf16(vl, bph, oacc[et], 0, 0, 0);
      }
    }
  }
  den += __shfl_xor(den, 16);
  den += __shfl_xor(den, 32);
  float inv = 1.f / den;
  int b = bh >> 3, h = bh & 7;
#pragma unroll
  for (int et = 0; et < 4; ++et) {
    ushort4 h4, l4;
    split2(oacc[et][0] * inv, h4.x, l4.x); split2(oacc[et][1] * inv, h4.y, l4.y);
    split2(oacc[et][2] * inv, h4.z, l4.z); split2(oacc[et][3] * inv, h4.w, l4.w);
    int kc = h * 2 + (et >> 1);
    int lu_f = (et & 1) * 2 + (lu >> 1), j0 = (lu & 1) * 4;
    size_t base = ((((size_t)(b * 64 + qt)) * 16 + kc) * 64 + lu_f * 16 + lr) * 8 + j0;
    *(ushort4*)(anfh + base) = h4;
    *(ushort4*)(anfl + base) = l4;
  }
}

// ---------------- FUSED dw3 + GELU -> fc2 B-frags directly
__global__ void k_dw3_frag(const float* __restrict__ X, const float* __restrict__ w,
                           const float* __restrict__ bias,
                           ushort* __restrict__ dh, ushort* __restrict__ dl) {
  int bid = blockIdx.x;               // 4096 = bg(8) x chg(128) x pch(4)
  int pch = bid & 3; bid >>= 2;
  int chg = bid & 127; int bg = bid >> 7;
  int tid = threadIdx.x;
  int n = pch * 256 + tid;
  int x = n & 31, y = n >> 5;
  int ch0 = chg * 8;
  V16u hi, lo;
#pragma unroll
  for (int jj = 0; jj < 8; ++jj) {
    int ch = ch0 + jj;
    const float* src = X + ((size_t)((bg << 10) + ch)) * HW;
    const float* wr = w + ch * 9;
    float acc = bias[ch];
#pragma unroll
    for (int ky = 0; ky < 3; ++ky) {
      int yy = y + ky - 1;
      if ((unsigned)yy < 32u) {
        const float* row = src + yy * 32;
#pragma unroll
        for (int kx = 0; kx < 3; ++kx) {
          int xx = x + kx - 1;
          if ((unsigned)xx < 32u) acc += row[xx] * wr[ky * 3 + kx];
        }
      }
    }
    split2(gelu_exact(acc), hi.u[jj], lo.u[jj]);
  }
  size_t base = ((((size_t)(bg * 64 + (n >> 4)) * 32 + (ch0 >> 5)) * 64)
                 + ((ch0 >> 3) & 3) * 16 + (n & 15)) * 8;
  *(int4*)(dh + base) = hi.i4;
  *(int4*)(dl + base) = lo.i4;
}

// ---------------- FUSED depthwise 9x9 + LN + GELU + [2,256] proj + tanh -> pos
__global__ void k_dw9cotail(const float* __restrict__ Xnc, const float* __restrict__ wt9,
                            const float* __restrict__ bias,
                            const float* __restrict__ lnw, const float* __restrict__ lnb,
                            const float* __restrict__ w2, float* __restrict__ pos) {
  int bid = blockIdx.x;               // 1024 = bg(8) x ptile(128)
  int pt = bid & 127; int bg = bid >> 7;
  int tid = threadIdx.x;              // = channel
  int y = pt >> 2, x0 = (pt & 3) * 8;
  float acc[8];
  float bs = bias[tid];
#pragma unroll
  for (int p = 0; p < 8; ++p) acc[p] = bs;
  const float* src = Xnc + (size_t)(bg << 10) * 256;
  for (int ky = 0; ky < 9; ++ky) {
    int yy = y + ky - 4;
    if ((unsigned)yy >= 32u) continue;
#pragma unroll
    for (int kx = 0; kx < 9; ++kx) {
      float wv = wt9[(ky * 9 + kx) * 256 + tid];
#pragma unroll
      for (int p = 0; p < 8; ++p) {
        int xx = x0 + p + kx - 4;
        if ((unsigned)xx < 32u)
          acc[p] += src[(size_t)(yy * 32 + xx) * 256 + tid] * wv;
      }
    }
  }
  __shared__ float rs[8][4], rs2[8][4], ro0[8][4], ro1[8][4];
  int wv = tid >> 6, ln = tid & 63;
  float lw = lnw[tid], lb = lnb[tid];
  float wa = w2[tid], wb = w2[256 + tid];
#pragma unroll
  for (int p = 0; p < 8; ++p) {
    float a = acc[p], b2 = acc[p] * acc[p];
#pragma unroll
    for (int off = 32; off; off >>= 1) { a += __shfl_xor(a, off); b2 += __shfl_xor(b2, off); }
    if (ln == 0) { rs[p][wv] = a; rs2[p][wv] = b2; }
  }
  __syncthreads();
#pragma unroll
  for (int p = 0; p < 8; ++p) {
    float tot  = rs[p][0] + rs[p][1] + rs[p][2] + rs[p][3];
    float tot2 = rs2[p][0] + rs2[p][1] + rs2[p][2] + rs2[p][3];
    float mean = tot * (1.f / 256.f);
    float rstd = rsqrtf(tot2 * (1.f / 256.f) - mean * mean + 1e-5f);
    float ge = gelu_exact((acc[p] - mean) * rstd * lw + lb);
    float o0 = ge * wa, o1 = ge * wb;
#pragma unroll
    for (int off = 32; off; off >>= 1) { o0 += __shfl_xor(o0, off); o1 += __shfl_xor(o1, off); }
    if (ln == 0) { ro0[p][wv] = o0; ro1[p][wv] = o1; }
  }
  __syncthreads();
  if (tid < 8) {
    int p = tid;
    float o0 = ro0[p][0] + ro0[p][1] + ro0[p][2] + ro0[p][3];
    float o1 = ro1[p][0] + ro1[p][1] + ro1[p][2] + ro1[p][3];
    float offy = tanhf(o0) * (2.f / 32.f);
    float offx = tanhf(o1) * (2.f / 32.f);
    int n = y * 32 + x0 + p;
    float refy = ((y + 0.5f) * (1.f / 32.f)) * 2.f - 1.f;
    float refx = ((x0 + p + 0.5f) * (1.f / 32.f)) * 2.f - 1.f;
    pos[((bg << 10) + n) * 2]     = offx + refx;
    pos[((bg << 10) + n) * 2 + 1] = offy + refy;
  }
}

// ---------------- FUSED bilinear grid sample -> kv-GEMM B-frags directly
__global__ void k_gsample_frag(const float* __restrict__ Xnc, const float* __restrict__ pos,
                               ushort* __restrict__ dh, ushort* __restrict__ dl) {
  int bid = blockIdx.x;               // 128 = bg(8) x nch(16)
  int nch = bid & 15; int bg = bid >> 4;
  int tid = threadIdx.x;              // channel c [0,256)
  __shared__ int sI[4][64];
  __shared__ float sW[4][64];
  if (tid < 64) {
    int j = nch * 64 + tid;
    float gx = pos[((bg << 10) + j) * 2];
    float gy = pos[((bg << 10) + j) * 2 + 1];
    float fx = (gx + 1.f) * 0.5f * 31.f;
    float fy = (gy + 1.f) * 0.5f * 31.f;
    float x0f = floorf(fx), y0f = floorf(fy);
    int x0 = (int)x0f, y0 = (int)y0f;
    float wx1 = fx - x0f, wx0 = 1.f - wx1;
    float wy1 = fy - y0f, wy0 = 1.f - wy1;
    bool vx0 = (x0 >= 0) & (x0 <= 31);
    bool vx1 = (x0 + 1 >= 0) & (x0 + 1 <= 31);
    bool vy0 = (y0 >= 0) & (y0 <= 31);
    bool vy1 = (y0 + 1 >= 0) & (y0 + 1 <= 31);
    int cx0 = min(max(x0, 0), 31), cx1 = min(max(x0 + 1, 0), 31);
    int cy0 = min(max(y0, 0), 31), cy1 = min(max(y0 + 1, 0), 31);
    sW[0][tid] = wx0 * wy0 * ((vx0 && vy0) ? 1.f : 0.f);
    sW[1][tid] = wx1 * wy0 * ((vx1 && vy0) ? 1.f : 0.f);
    sW[2][tid] = wx0 * wy1 * ((vx0 && vy1) ? 1.f : 0.f);
    sW[3][tid] = wx1 * wy1 * ((vx1 && vy1) ? 1.f : 0.f);
    sI[0][tid] = cy0 * 32 + cx0; sI[1][tid] = cy0 * 32 + cx1;
    sI[2][tid] = cy1 * 32 + cx0; sI[3][tid] = cy1 * 32 + cx1;
  }
  __syncthreads();
  int b = bg >> 1, g = bg & 1;
  const float* src = Xnc + (size_t)(bg << 10) * 256;
  for (int nn = 0; nn < 64; ++nn) {
    float acc = src[(size_t)sI[0][nn] * 256 + tid] * sW[0][nn]
              + src[(size_t)sI[1][nn] * 256 + tid] * sW[1][nn]
              + src[(size_t)sI[2][nn] * 256 + tid] * sW[2][nn]
              + src[(size_t)sI[3][nn] * 256 + tid] * sW[3][nn];
    ushort h, l; split2(acc, h, l);
    int jglob = nch * 64 + nn;
    size_t addr = ((((size_t)(b * 64 + (jglob >> 4)) * 16) + g * 8 + (tid >> 5)) * 64
                   + ((tid >> 3) & 3) * 16 + (jglob & 15)) * 8 + (tid & 7);
    dh[addr] = h; dl[addr] = l;
  }
}

// ---------------------------------------------------------------------------
extern "C" void kernel_launch(void* const* d_in, const int* in_sizes, int n_in,
                              void* d_out, int out_size, void* d_ws, size_t ws_size,
                              hipStream_t stream) {
  const float* tgt    = (const float*)d_in[0];
  const float* refp   = (const float*)d_in[1];
  const float* emb_w  = (const float*)d_in[2];
  const float* emb_b  = (const float*)d_in[3];
  const float* q_w    = (const float*)d_in[4];
  const float* q_b    = (const float*)d_in[5];
  const float* k_w    = (const float*)d_in[6];
  const float* k_b    = (const float*)d_in[7];
  const float* v_w    = (const float*)d_in[8];
  const float* v_b    = (const float*)d_in[9];
  const float* out_w  = (const float*)d_in[10];
  const float* out_b  = (const float*)d_in[11];
  const float* ln1_w  = (const float*)d_in[12];
  const float* ln1_b  = (const float*)d_in[13];
  const float* n1_w   = (const float*)d_in[14];
  const float* n1_b   = (const float*)d_in[15];
  const float* mbq_w  = (const float*)d_in[16];
  const float* mbq_b  = (const float*)d_in[17];
  const float* mbkv_w = (const float*)d_in[18];
  const float* mbkv_b = (const float*)d_in[19];
  const float* mbp_w  = (const float*)d_in[20];
  const float* mbp_b  = (const float*)d_in[21];
  const float* n2_w   = (const float*)d_in[22];
  const float* n2_b   = (const float*)d_in[23];
  const float* fc1_w  = (const float*)d_in[24];
  const float* fc1_b  = (const float*)d_in[25];
  const float* dw3_w  = (const float*)d_in[26];
  const float* dw3_b  = (const float*)d_in[27];
  const float* fc2_w  = (const float*)d_in[28];
  const float* fc2_b  = (const float*)d_in[29];
  const float* dw9_w  = (const float*)d_in[30];
  const float* dw9_b  = (const float*)d_in[31];
  const float* coln_w = (const float*)d_in[32];
  const float* coln_b = (const float*)d_in[33];
  const float* coout_w= (const float*)d_in[34];

  float* ws = (float*)d_ws;
  float* slabA = ws + 0;
  float* qfrag = ws + 2097152;
  float* xbuf  = ws + 4194304;
  float* slabF = ws + 10485760;
  float* slabG = ws + 14680064;
  float* slabH = ws + 23068672;
  float* featnc= ws + 31457280;
  float* posb  = ws + 35389440;
  float* wt9   = ws + 35405824;
  float* biasmb= ws + 35426560;
  float* biaskv= ws + 35427328;
  float* biasq = ws + 35428352;

  ushort* XtH = (ushort*)(ws + 4194304);
  ushort* XtL = XtH + 4734976;
  ushort* WtEH = (ushort*)slabG;
  ushort* WtEL = WtEH + 4718592;
  float* part = slabH;
  ushort* tgtfh = (ushort*)slabF;
  ushort* tgtfl = tgtfh + 2097152;

  // weight frags (slab J)
  ushort* J = (ushort*)(ws + 33554432);
  ushort* wfq_h   = J;                ushort* wfq_l   = J + 262144;
  ushort* wfkv_h  = J + 524288;       ushort* wfkv_l  = J + 1048576;
  ushort* wfo_h   = J + 1572864;      ushort* wfo_l   = J + 1835008;
  ushort* wfmqkv_h= J + 2097152;      ushort* wfmqkv_l= J + 2293760;
  ushort* wfmp_h  = J + 2490368;      ushort* wfmp_l  = J + 2555904;
  ushort* wff1_h  = J + 2621440;      ushort* wff1_l  = J + 2883584;
  ushort* wff2_h  = J + 3145728;      ushort* wff2_l  = J + 3407872;

  // phase pointers
  ushort* hfh = (ushort*)slabH;     ushort* hfl = hfh + 2097152;   // n1 frags (part dead)
  ushort* mQh = (ushort*)slabG;     ushort* mQl = mQh + 2097152;
  ushort* mKh = mQh + 4194304;      ushort* mKl = mQh + 6291456;
  ushort* mVh = mQh + 8388608;      ushort* mVl = mQh + 10485760;
  ushort* ofh = (ushort*)slabF;     ushort* ofl = ofh + 2097152;   // mb out frags
  ushort* h2fh = (ushort*)slabF;    ushort* h2fl = h2fh + 2097152;
  float* m_cm = slabG;
  ushort* mifh = (ushort*)slabH;    ushort* mifl = mifh + 8388608;
  float* offin = slabA;
  ushort* sfh = (ushort*)slabF;     ushort* sfl = sfh + 2097152;
  ushort* aQh = (ushort*)qfrag;     ushort* aQl = aQh + 2097152;
  ushort* aKh = (ushort*)slabG;     ushort* aKl = aKh + 2097152;
  ushort* aVh = aKh + 4194304;      ushort* aVl = aKh + 6291456;
  ushort* anfh = (ushort*)slabH;    ushort* anfl = anfh + 2097152;

  // --- step 0: mega-prep (incl. tgt frags) ---
  k_prep_all<<<6370, 256, 0, stream>>>(
      emb_w, tgt, refp, q_w, k_w, v_w, out_w, mbq_w, mbkv_w, mbp_w, fc1_w, fc2_w,
      dw9_w, q_b, mbq_b, mbkv_b, k_b, v_b,
      WtEH, WtEL, XtH, XtL,
      wfq_h, wfq_l, wfkv_h, wfkv_l, wfo_h, wfo_l, wfmqkv_h, wfmqkv_l,
      wfmp_h, wfmp_l, wff1_h, wff1_l, wff2_h, wff2_l,
      wt9, biasmb, biaskv, biasq, tgtfh, tgtfl);
  // --- step 1: emb conv (R13 tile) + merge ---
  k_emb_mfma<<<512, 256, 0, stream>>>(XtH, XtL, WtEH, WtEL, part);
  k_embmerge_nc<<<512, 256, 0, stream>>>(part, emb_b, featnc);
  // --- step 2: q proj -> main Q frags directly (scale folded) ---
  k_gemm_frag_main<<<512, 256, 0, stream>>>(wfq_h, wfq_l, tgtfh, tgtfl, biasq,
                                            aQh, aQl, aVh, aVl, 512, 16, 8);
  // --- step 3+4: fused ln1 -> xbuf + n1 -> frags (slabH) ---
  k_ln1n1<<<2048, 256, 0, stream>>>(featnc, ln1_w, ln1_b, n1_w, n1_b, xbuf, hfh, hfl);
  // --- step 5+6a: mqkv GEMM -> mb Q/K/V frags directly ---
  k_gemm_frag_mb<<<1536, 256, 0, stream>>>(wfmqkv_h, wfmqkv_l, hfh, hfl, biasmb,
                                           mQh, mQl, mKh, mKl, mVh, mVl);
  // --- step 6: mb attention ---
  k_mbattn_mfma<<<1024, 256, 0, stream>>>(mQh, mQl, mKh, mKl, mVh, mVl, ofh, ofl);
  // --- step 7: mbproj GEMM + residual-add into xbuf (fused) ---
  k_gemm_resadd<<<512, 256, 0, stream>>>(wfmp_h, wfmp_l, ofh, ofl, mbp_b,
                                         xbuf, xbuf, 8, 4, 1);
  // --- step 8: n2 -> h2 frags ---
  k_ln_frag<<<2048, 256, 0, stream>>>(xbuf, n2_w, n2_b, h2fh, h2fl, 1e-6f);
  // --- step 9: fc1 -> m_cm (slabG) ---
  k_gemm_mfma<<<2048, 256, 0, stream>>>(wff1_h, wff1_l, h2fh, h2fl, fc1_b, m_cm, 8, 16, 1024);
  // --- step 10: dw3 + gelu -> fc2 B-frags directly (slabH) ---
  k_dw3_frag<<<4096, 256, 0, stream>>>(m_cm, dw3_w, dw3_b, mifh, mifl);
  // --- step 11: fc2 GEMM + residual -> offin nc (fused) ---
  k_gemm_resadd<<<512, 256, 0, stream>>>(wff2_h, wff2_l, mifh, mifl, fc2_b,
                                         xbuf, offin, 32, 4, 0);
  // --- step 12+13: dw9 + cotail fused -> pos ---
  k_dw9cotail<<<1024, 256, 0, stream>>>(offin, wt9, dw9_b, coln_w, coln_b, coout_w, posb);
  // --- step 14+15a: grid sample -> kv B-frags directly (slabF) ---
  k_gsample_frag<<<128, 256, 0, stream>>>(featnc, posb, sfh, sfl);
  // --- step 15+16a: k+v GEMM -> main K frags + V^T frags directly ---
  k_gemm_frag_main<<<1024, 256, 0, stream>>>(wfkv_h, wfkv_l, sfh, sfl, biaskv,
                                             aKh, aKl, aVh, aVl, 512, 16, 16);
  // --- step 16: main attention ---
  k_mainattn_mfma<<<512, 256, 0, stream>>>(aQh, aQl, aKh, aKl, aVh, aVl, anfh, anfl);
  // --- step 17: out proj -> d_out ---
  k_gemm_mfma<<<512, 256, 0, stream>>>(wfo_h, wfo_l, anfh, anfl, out_b, (float*)d_out, 16, 8, 512);
}